// Round 5
// baseline (206.299 us; speedup 1.0000x reference)
//
#include <hip/hip_runtime.h>

#define NDIM 4096
#define LDIM 128
#define EDIM 12
#define HDIM 32
#define NT   4        // n-columns per block, one per wave
#define XSLOT 13      // float4 slots per l-row in staged tile (12 used + 1 pad)

typedef float f2 __attribute__((ext_vector_type(2)));

#ifndef __has_builtin
#define __has_builtin(x) 0
#endif

__device__ __forceinline__ float ex2_(float v) {
#if __has_builtin(__builtin_amdgcn_exp2f)
    return __builtin_amdgcn_exp2f(v);
#else
    return exp2f(v);
#endif
}
__device__ __forceinline__ float rcp_(float v) {
#if __has_builtin(__builtin_amdgcn_rcpf)
    return __builtin_amdgcn_rcpf(v);
#else
    return 1.0f / v;
#endif
}
__device__ __forceinline__ float rsq_(float v) {
#if __has_builtin(__builtin_amdgcn_rsqf)
    return __builtin_amdgcn_rsqf(v);
#else
    return rsqrtf(v);
#endif
}
// tanh(v) = 1 - 2/(e^{2v}+1)
__device__ __forceinline__ float tanh_(float v) {
    float t = ex2_(v * 2.8853900817779268f);
    return 1.0f - 2.0f * rcp_(t + 1.0f);
}

__device__ __forceinline__ f2 lo2(float4 v) { f2 r; r.x = v.x; r.y = v.y; return r; }
__device__ __forceinline__ f2 hi2(float4 v) { f2 r; r.x = v.z; r.y = v.w; return r; }
__device__ __forceinline__ f2 pf(f2 a, f2 b, f2 c) { return __builtin_elementwise_fma(a, b, c); }

// unpack bf16 pair (packed uint) -> f2
__device__ __forceinline__ f2 up2(unsigned int u) {
    f2 r;
    r.x = __uint_as_float(u << 16);
    r.y = __uint_as_float(u & 0xffff0000u);
    return r;
}
// round-to-nearest-even f32 pair -> packed bf16 uint
__device__ __forceinline__ unsigned int bfpair(float lo, float hi) {
    unsigned int a = __float_as_uint(lo), b = __float_as_uint(hi);
    a = (a + 0x7fffu + ((a >> 16) & 1u)) >> 16;
    b = (b + 0x7fffu + ((b >> 16) & 1u)) >> 16;
    return a | (b << 16);
}

// dot(12-elem weight row (global, uniform -> s_load), f2[6]) via packed fma
__device__ __forceinline__ float dot12p(const float* __restrict__ w, const f2* v) {
    const float4* w4 = reinterpret_cast<const float4*>(w);
    float4 a = w4[0], b = w4[1], c = w4[2];
    f2 s = v[0] * lo2(a);
    s = pf(v[1], hi2(a), s);
    s = pf(v[2], lo2(b), s);
    s = pf(v[3], hi2(b), s);
    s = pf(v[4], lo2(c), s);
    s = pf(v[5], hi2(c), s);
    return s.x + s.y;
}
__device__ __forceinline__ float dot32p(const float* __restrict__ w, const f2* v) {
    const float4* w4 = reinterpret_cast<const float4*>(w);
    f2 s = {0.f, 0.f};
    #pragma unroll
    for (int c = 0; c < 8; ++c) {
        float4 t = w4[c];
        s = pf(v[2*c],   lo2(t), s);
        s = pf(v[2*c+1], hi2(t), s);
    }
    return s.x + s.y;
}

__global__ __launch_bounds__(256, 3)
void encoder_fused(const float* __restrict__ x,
                   const float* __restrict__ inw, const float* __restrict__ inb,
                   const float* __restrict__ ow,  const float* __restrict__ ob,
                   const float* __restrict__ w1,  const float* __restrict__ b1,
                   const float* __restrict__ w2,  const float* __restrict__ b2,
                   const float* __restrict__ w3,  const float* __restrict__ b3,
                   const float* __restrict__ g1,  const float* __restrict__ be1,
                   const float* __restrict__ g2,  const float* __restrict__ be2,
                   float* __restrict__ out)
{
    const int t  = threadIdx.x;
    const int w  = t >> 6;        // wave id 0..3 -> n_local
    const int ln = t & 63;        // lane; handles rows ln and ln+64
    const int n0 = blockIdx.x * NT;

    __shared__ float4       sX[LDIM * XSLOT];     // 26 KB staged x / out tile
    __shared__ unsigned int sKV[NT][LDIM][12];    // 24 KB bf16 K|V records

    // ---- cooperative coalesced load of x tile (192B aligned chunks per l) ----
    const float4* xg = reinterpret_cast<const float4*>(x);
    #pragma unroll
    for (int j = 0; j < 6; ++j) {
        int i = t + 256 * j;                  // logical f4 index, < 1536
        int l = i / 12, r = i - l * 12;       // r = n_local*3 + c
        sX[l * XSLOT + r] = xg[(size_t)l * (NDIM * 3) + n0 * 3 + r];
    }
    __syncthreads();

    const float SCALE = 0.2886751345948129f;   // 1/sqrt(12)
    const float L2E   = 1.4426950408889634f;

    // ---- phase 1: QKV projection, pack K/V into LDS ----
    f2 xr[2][6];
    f2 qL[2][6];                  // q * SCALE * L2E
    float qq[2];
    float knmx = 0.f;
    #pragma unroll
    for (int rr = 0; rr < 2; ++rr) {
        const int row = ln + 64 * rr;
        float4 xa = sX[row * XSLOT + w * 3 + 0];
        float4 xb = sX[row * XSLOT + w * 3 + 1];
        float4 xc = sX[row * XSLOT + w * 3 + 2];
        xr[rr][0] = lo2(xa); xr[rr][1] = hi2(xa);
        xr[rr][2] = lo2(xb); xr[rr][3] = hi2(xb);
        xr[rr][4] = lo2(xc); xr[rr][5] = hi2(xc);

        float aq = 0.f;
        #pragma unroll
        for (int f = 0; f < EDIM; f += 2) {
            float a0 = (inb[f]     + dot12p(inw + f * EDIM,       xr[rr])) * SCALE;
            float a1 = (inb[f + 1] + dot12p(inw + (f + 1) * EDIM, xr[rr])) * SCALE;
            aq += a0 * a0 + a1 * a1;
            f2 tq; tq.x = a0 * L2E; tq.y = a1 * L2E;
            qL[rr][f >> 1] = tq;
        }
        qq[rr] = aq;

        float kv[EDIM];
        float kn = 0.f;
        #pragma unroll
        for (int f = 0; f < EDIM; ++f) {
            float a = inb[12 + f] + dot12p(inw + (12 + f) * EDIM, xr[rr]);
            kv[f] = a; kn += a * a;
        }
        knmx = fmaxf(knmx, kn);
        unsigned int u0 = bfpair(kv[0], kv[1]),  u1 = bfpair(kv[2], kv[3]),
                     u2 = bfpair(kv[4], kv[5]),  u3 = bfpair(kv[6], kv[7]),
                     u4 = bfpair(kv[8], kv[9]),  u5 = bfpair(kv[10], kv[11]);
        #pragma unroll
        for (int f = 0; f < EDIM; ++f)
            kv[f] = inb[24 + f] + dot12p(inw + (24 + f) * EDIM, xr[rr]);
        unsigned int u6 = bfpair(kv[0], kv[1]),  u7 = bfpair(kv[2], kv[3]),
                     u8 = bfpair(kv[4], kv[5]),  u9 = bfpair(kv[6], kv[7]),
                     uA = bfpair(kv[8], kv[9]),  uB = bfpair(kv[10], kv[11]);
        *reinterpret_cast<uint4*>(&sKV[w][row][0]) = make_uint4(u0, u1, u2, u3);
        *reinterpret_cast<uint4*>(&sKV[w][row][4]) = make_uint4(u4, u5, u6, u7);
        *reinterpret_cast<uint4*>(&sKV[w][row][8]) = make_uint4(u8, u9, uA, uB);
    }

    // wave-local max ||k||^2 over this n's 128 rows
    float mk = knmx;
    #pragma unroll
    for (int off = 32; off > 0; off >>= 1) mk = fmaxf(mk, __shfl_xor(mk, off));
    // Cauchy-Schwarz bound in log2 domain: s*L2E - M2 <= 0
    const float M20 = sqrtf(qq[0] * mk) * L2E;
    const float M21 = sqrtf(qq[1] * mk) * L2E;

    __syncthreads();   // sKV complete; all phase-1 sX reads done

    // ---- attention: 3 broadcast b128 per m serve both rows ----
    f2 acc0[6], acc1[6];
    #pragma unroll
    for (int j = 0; j < 6; ++j) {
        acc0[j].x = 0.f; acc0[j].y = 0.f;
        acc1[j].x = 0.f; acc1[j].y = 0.f;
    }
    float psum0 = 0.f, psum1 = 0.f;

    #pragma unroll 2
    for (int m = 0; m < LDIM; ++m) {
        uint4 A = *reinterpret_cast<const uint4*>(&sKV[w][m][0]);
        uint4 B = *reinterpret_cast<const uint4*>(&sKV[w][m][4]);
        uint4 C = *reinterpret_cast<const uint4*>(&sKV[w][m][8]);
        f2 k0 = up2(A.x), k1 = up2(A.y), k2 = up2(A.z),
           k3 = up2(A.w), k4 = up2(B.x), k5 = up2(B.y);
        f2 s0 = qL[0][0] * k0;
        s0 = pf(qL[0][1], k1, s0);
        s0 = pf(qL[0][2], k2, s0);
        s0 = pf(qL[0][3], k3, s0);
        s0 = pf(qL[0][4], k4, s0);
        s0 = pf(qL[0][5], k5, s0);
        f2 s1 = qL[1][0] * k0;
        s1 = pf(qL[1][1], k1, s1);
        s1 = pf(qL[1][2], k2, s1);
        s1 = pf(qL[1][3], k3, s1);
        s1 = pf(qL[1][4], k4, s1);
        s1 = pf(qL[1][5], k5, s1);
        float pe0 = ex2_(s0.x + s0.y - M20);
        float pe1 = ex2_(s1.x + s1.y - M21);
        psum0 += pe0;
        psum1 += pe1;
        f2 v0 = up2(B.z), v1 = up2(B.w), v2 = up2(C.x),
           v3 = up2(C.y), v4 = up2(C.z), v5 = up2(C.w);
        f2 pp0; pp0.x = pe0; pp0.y = pe0;
        f2 pp1; pp1.x = pe1; pp1.y = pe1;
        acc0[0] = pf(pp0, v0, acc0[0]); acc1[0] = pf(pp1, v0, acc1[0]);
        acc0[1] = pf(pp0, v1, acc0[1]); acc1[1] = pf(pp1, v1, acc1[1]);
        acc0[2] = pf(pp0, v2, acc0[2]); acc1[2] = pf(pp1, v2, acc1[2]);
        acc0[3] = pf(pp0, v3, acc0[3]); acc1[3] = pf(pp1, v3, acc1[3]);
        acc0[4] = pf(pp0, v4, acc0[4]); acc1[4] = pf(pp1, v4, acc1[4]);
        acc0[5] = pf(pp0, v5, acc0[5]); acc1[5] = pf(pp1, v5, acc1[5]);
    }

    // ---- per-row epilogue: out-proj + LN1 + MLP + LN2 -> z tile ----
    #pragma unroll
    for (int rr = 0; rr < 2; ++rr) {
        const float psum = rr ? psum1 : psum0;
        const float inv = rcp_(fmaxf(psum, 1e-35f));
        f2 at[6];
        #pragma unroll
        for (int j = 0; j < 6; ++j) {
            f2 a = rr ? acc1[j] : acc0[j];
            at[j].x = a.x * inv; at[j].y = a.y * inv;
        }

        f2 r[6];
        #pragma unroll
        for (int f = 0; f < EDIM; f += 2) {
            float a0 = ob[f]     + dot12p(ow + f * EDIM,       at);
            float a1 = ob[f + 1] + dot12p(ow + (f + 1) * EDIM, at);
            f2 tr; tr.x = a0; tr.y = a1;
            r[f >> 1] = xr[rr][f >> 1] + tr;
        }
        f2 sm = r[0] + r[1] + r[2] + r[3] + r[4] + r[5];
        float mu = (sm.x + sm.y) * (1.0f / 12.0f);
        f2 mub; mub.x = mu; mub.y = mu;
        f2 vs = {0.f, 0.f};
        #pragma unroll
        for (int j = 0; j < 6; ++j) { f2 d = r[j] - mub; vs = pf(d, d, vs); }
        float rs = rsq_((vs.x + vs.y) * (1.0f / 12.0f) + 1e-5f);
        f2 rsb; rsb.x = rs; rsb.y = rs;
        const f2* g1p  = reinterpret_cast<const f2*>(g1);
        const f2* be1p = reinterpret_cast<const f2*>(be1);
        f2 y[6];
        #pragma unroll
        for (int j = 0; j < 6; ++j)
            y[j] = pf((r[j] - mub) * rsb, g1p[j], be1p[j]);

        f2 h1[16];
        #pragma unroll
        for (int h = 0; h < HDIM; h += 2) {
            float a0 = tanh_(b1[h]     + dot12p(w1 + h * EDIM,       y));
            float a1 = tanh_(b1[h + 1] + dot12p(w1 + (h + 1) * EDIM, y));
            f2 th; th.x = a0; th.y = a1;
            h1[h >> 1] = th;
        }
        f2 h2[16];
        #pragma unroll
        for (int g = 0; g < HDIM; g += 2) {
            float a0 = tanh_(b2[g]     + dot32p(w2 + g * HDIM,       h1));
            float a1 = tanh_(b2[g + 1] + dot32p(w2 + (g + 1) * HDIM, h1));
            f2 th; th.x = a0; th.y = a1;
            h2[g >> 1] = th;
        }
        f2 r2[6];
        #pragma unroll
        for (int e = 0; e < EDIM; e += 2) {
            float a0 = tanh_(b3[e]     + dot32p(w3 + e * HDIM,       h2));
            float a1 = tanh_(b3[e + 1] + dot32p(w3 + (e + 1) * HDIM, h2));
            f2 th; th.x = a0; th.y = a1;
            r2[e >> 1] = y[e >> 1] + th;
        }

        f2 sm2 = r2[0] + r2[1] + r2[2] + r2[3] + r2[4] + r2[5];
        float mu2 = (sm2.x + sm2.y) * (1.0f / 12.0f);
        f2 mub2; mub2.x = mu2; mub2.y = mu2;
        f2 vs2 = {0.f, 0.f};
        #pragma unroll
        for (int j = 0; j < 6; ++j) { f2 d = r2[j] - mub2; vs2 = pf(d, d, vs2); }
        float rs2 = rsq_((vs2.x + vs2.y) * (1.0f / 12.0f) + 1e-5f);
        f2 rsb2; rsb2.x = rs2; rsb2.y = rs2;
        const f2* g2p  = reinterpret_cast<const f2*>(g2);
        const f2* be2p = reinterpret_cast<const f2*>(be2);
        f2 z[6];
        #pragma unroll
        for (int j = 0; j < 6; ++j)
            z[j] = pf((r2[j] - mub2) * rsb2, g2p[j], be2p[j]);

        const int base = (ln + 64 * rr) * XSLOT + w * 3;
        sX[base + 0] = make_float4(z[0].x, z[0].y, z[1].x, z[1].y);
        sX[base + 1] = make_float4(z[2].x, z[2].y, z[3].x, z[3].y);
        sX[base + 2] = make_float4(z[4].x, z[4].y, z[5].x, z[5].y);
    }

    __syncthreads();

    // ---- cooperative coalesced store of out tile ----
    float4* og = reinterpret_cast<float4*>(out);
    #pragma unroll
    for (int j = 0; j < 6; ++j) {
        int i = t + 256 * j;
        int l = i / 12, r = i - l * 12;
        og[(size_t)l * (NDIM * 3) + n0 * 3 + r] = sX[l * XSLOT + r];
    }
}

extern "C" void kernel_launch(void* const* d_in, const int* in_sizes, int n_in,
                              void* d_out, int out_size, void* d_ws, size_t ws_size,
                              hipStream_t stream) {
    const float* x   = (const float*)d_in[0];
    const float* inw = (const float*)d_in[1];
    const float* inb = (const float*)d_in[2];
    const float* ow  = (const float*)d_in[3];
    const float* ob  = (const float*)d_in[4];
    const float* w1  = (const float*)d_in[5];
    const float* b1  = (const float*)d_in[6];
    const float* w2  = (const float*)d_in[7];
    const float* b2  = (const float*)d_in[8];
    const float* w3  = (const float*)d_in[9];
    const float* b3  = (const float*)d_in[10];
    const float* g1  = (const float*)d_in[11];
    const float* be1 = (const float*)d_in[12];
    const float* g2  = (const float*)d_in[13];
    const float* be2 = (const float*)d_in[14];
    float* out = (float*)d_out;

    encoder_fused<<<dim3(NDIM / NT), dim3(256), 0, stream>>>(
        x, inw, inb, ow, ob, w1, b1, w2, b2, w3, b3, g1, be1, g2, be2, out);
}

// Round 6
// 201.580 us; speedup vs baseline: 1.0234x; 1.0234x over previous
//
#include <hip/hip_runtime.h>

#define NDIM 4096
#define LDIM 128
#define EDIM 12
#define HDIM 32
#define NT   4        // n per block, one per wave
#define XSLOT 13      // float4 slots per l-row in staged x/out tile

typedef float    f2 __attribute__((ext_vector_type(2)));
typedef _Float16 h2 __attribute__((ext_vector_type(2)));

#ifndef __has_builtin
#define __has_builtin(x) 0
#endif

__device__ __forceinline__ float ex2_(float v) {
#if __has_builtin(__builtin_amdgcn_exp2f)
    return __builtin_amdgcn_exp2f(v);
#else
    return exp2f(v);
#endif
}
__device__ __forceinline__ float rcp_(float v) {
#if __has_builtin(__builtin_amdgcn_rcpf)
    return __builtin_amdgcn_rcpf(v);
#else
    return 1.0f / v;
#endif
}
__device__ __forceinline__ float rsq_(float v) {
#if __has_builtin(__builtin_amdgcn_rsqf)
    return __builtin_amdgcn_rsqf(v);
#else
    return rsqrtf(v);
#endif
}
// tanh(v) = 1 - 2/(e^{2v}+1)
__device__ __forceinline__ float tanh_(float v) {
    float t = ex2_(v * 2.8853900817779268f);
    return 1.0f - 2.0f * rcp_(t + 1.0f);
}

__device__ __forceinline__ f2 lo2(float4 v) { f2 r; r.x = v.x; r.y = v.y; return r; }
__device__ __forceinline__ f2 hi2(float4 v) { f2 r; r.x = v.z; r.y = v.w; return r; }
__device__ __forceinline__ f2 pf(f2 a, f2 b, f2 c) { return __builtin_elementwise_fma(a, b, c); }

// f32 pair -> packed f16 (RTZ single-instruction when available)
__device__ __forceinline__ h2 pk16(float a, float b) {
#if __has_builtin(__builtin_amdgcn_cvt_pkrtz)
    return __builtin_bit_cast(h2, __builtin_amdgcn_cvt_pkrtz(a, b));
#else
    h2 r; r.x = (_Float16)a; r.y = (_Float16)b; return r;
#endif
}
// v_dot2_f32_f16: a.x*b.x + a.y*b.y + c
__device__ __forceinline__ float fd2(h2 a, h2 b, float c) {
#if __has_builtin(__builtin_amdgcn_fdot2)
    return __builtin_amdgcn_fdot2(a, b, c, false);
#else
    return (float)a.x * (float)b.x + (float)a.y * (float)b.y + c;
#endif
}
__device__ __forceinline__ unsigned int h2u(h2 a) { return __builtin_bit_cast(unsigned int, a); }
__device__ __forceinline__ h2 u2h(unsigned int a) { return __builtin_bit_cast(h2, a); }

// dot(12-elem weight row (global, uniform -> s_load), f2[6]) via packed fma
__device__ __forceinline__ float dot12p(const float* __restrict__ w, const f2* v) {
    const float4* w4 = reinterpret_cast<const float4*>(w);
    float4 a = w4[0], b = w4[1], c = w4[2];
    f2 s = v[0] * lo2(a);
    s = pf(v[1], hi2(a), s);
    s = pf(v[2], lo2(b), s);
    s = pf(v[3], hi2(b), s);
    s = pf(v[4], lo2(c), s);
    s = pf(v[5], hi2(c), s);
    return s.x + s.y;
}
__device__ __forceinline__ float dot32p(const float* __restrict__ w, const f2* v) {
    const float4* w4 = reinterpret_cast<const float4*>(w);
    f2 s = {0.f, 0.f};
    #pragma unroll
    for (int c = 0; c < 8; ++c) {
        float4 t = w4[c];
        s = pf(v[2*c],   lo2(t), s);
        s = pf(v[2*c+1], hi2(t), s);
    }
    return s.x + s.y;
}

__global__ __launch_bounds__(256, 3)
void encoder_fused(const float* __restrict__ x,
                   const float* __restrict__ inw, const float* __restrict__ inb,
                   const float* __restrict__ ow,  const float* __restrict__ ob,
                   const float* __restrict__ w1,  const float* __restrict__ b1,
                   const float* __restrict__ w2,  const float* __restrict__ b2,
                   const float* __restrict__ w3,  const float* __restrict__ b3,
                   const float* __restrict__ g1,  const float* __restrict__ be1,
                   const float* __restrict__ g2,  const float* __restrict__ be2,
                   float* __restrict__ out)
{
    const int t  = threadIdx.x;
    const int w  = t >> 6;        // wave id = n_local
    const int ln = t & 63;        // lane; owns rows ln and ln+64
    const int n0 = blockIdx.x * NT;

    __shared__ float4 sX[LDIM * XSLOT];          // 26 KB staged x / out tile
    // per m-pair 96B record: words 0-11 V interleaved (v2[e]=(v_m0[e],v_m1[e])),
    // words 12-17 K_m0 (f16 pairs along e), words 18-23 K_m1
    __shared__ unsigned int sKV[NT * 64 * 24];   // 24 KB

    // ---- cooperative coalesced load of x tile ----
    const float4* xg = reinterpret_cast<const float4*>(x);
    #pragma unroll
    for (int j = 0; j < 6; ++j) {
        int i = t + 256 * j;                  // < 1536
        int l = i / 12, r = i - l * 12;
        sX[l * XSLOT + r] = xg[(size_t)l * (NDIM * 3) + n0 * 3 + r];
    }
    __syncthreads();

    const float SCALE = 0.2886751345948129f;   // 1/sqrt(12)
    const float L2E   = 1.4426950408889634f;
    const float SL2E  = SCALE * L2E;

    // ---- phase A: QKV projection, pack f16 K|V records ----
    h2 q2[2][6];                 // q * SCALE * L2E, packed f16
    float qq[2];
    float knmx = 0.f;
    #pragma unroll
    for (int rr = 0; rr < 2; ++rr) {
        const int row = ln + 64 * rr;
        float4 xa = sX[row * XSLOT + w * 3 + 0];
        float4 xb = sX[row * XSLOT + w * 3 + 1];
        float4 xc = sX[row * XSLOT + w * 3 + 2];
        f2 xr[6] = {lo2(xa), hi2(xa), lo2(xb), hi2(xb), lo2(xc), hi2(xc)};

        float aq = 0.f;
        #pragma unroll
        for (int f = 0; f < EDIM; f += 2) {
            float a0 = (inb[f]     + dot12p(inw + f * EDIM,       xr)) * SCALE;
            float a1 = (inb[f + 1] + dot12p(inw + (f + 1) * EDIM, xr)) * SCALE;
            aq += a0 * a0 + a1 * a1;
            q2[rr][f >> 1] = pk16(a0 * L2E, a1 * L2E);
        }
        qq[rr] = aq;

        float kv[EDIM];
        float kn = 0.f;
        #pragma unroll
        for (int f = 0; f < EDIM; ++f) {
            float a = inb[12 + f] + dot12p(inw + (12 + f) * EDIM, xr);
            kv[f] = a; kn += a * a;
        }
        knmx = fmaxf(knmx, kn);
        unsigned int kw[6];
        #pragma unroll
        for (int j = 0; j < 6; ++j) kw[j] = h2u(pk16(kv[2*j], kv[2*j+1]));

        #pragma unroll
        for (int f = 0; f < EDIM; ++f)
            kv[f] = inb[24 + f] + dot12p(inw + (24 + f) * EDIM, xr);
        unsigned int vw[6], ov[6];
        #pragma unroll
        for (int j = 0; j < 6; ++j) vw[j] = h2u(pk16(kv[2*j], kv[2*j+1]));
        #pragma unroll
        for (int j = 0; j < 6; ++j) ov[j] = __shfl_xor(vw[j], 1);

        const int pr = (ln >> 1) + 32 * rr;
        unsigned int* rec = &sKV[(w * 64 + pr) * 24];
        if (!(ln & 1)) {
            // even lane = m0; neighbor = m1: interleave V across the pair
            unsigned int vi[12];
            #pragma unroll
            for (int j = 0; j < 6; ++j) {
                vi[2*j]   = (vw[j] & 0xffffu)  | (ov[j] << 16);
                vi[2*j+1] = (vw[j] >> 16)      | (ov[j] & 0xffff0000u);
            }
            *reinterpret_cast<uint4*>(&rec[0])  = make_uint4(vi[0], vi[1], vi[2],  vi[3]);
            *reinterpret_cast<uint4*>(&rec[4])  = make_uint4(vi[4], vi[5], vi[6],  vi[7]);
            *reinterpret_cast<uint4*>(&rec[8])  = make_uint4(vi[8], vi[9], vi[10], vi[11]);
            *reinterpret_cast<uint4*>(&rec[12]) = make_uint4(kw[0], kw[1], kw[2], kw[3]);
            *reinterpret_cast<uint2*>(&rec[16]) = make_uint2(kw[4], kw[5]);
        } else {
            *reinterpret_cast<uint2*>(&rec[18]) = make_uint2(kw[0], kw[1]);
            *reinterpret_cast<uint2*>(&rec[20]) = make_uint2(kw[2], kw[3]);
            *reinterpret_cast<uint2*>(&rec[22]) = make_uint2(kw[4], kw[5]);
        }
    }

    // wave-local max ||k||^2 over this n's 128 rows
    float mk = knmx;
    #pragma unroll
    for (int off = 32; off > 0; off >>= 1) mk = fmaxf(mk, __shfl_xor(mk, off));
    // Cauchy-Schwarz bound in log2 domain: s - M2 <= ~0
    float M2v[2];
    M2v[0] = sqrtf(qq[0] * mk) * L2E;
    M2v[1] = sqrtf(qq[1] * mk) * L2E;
    // (no block barrier needed: sKV is wave-local; in-wave LDS RAW is ordered)

    // ---- attention: 6 broadcast b128 per m-PAIR serve both rows ----
    float acc[2][EDIM];
    #pragma unroll
    for (int rr = 0; rr < 2; ++rr)
        #pragma unroll
        for (int e = 0; e < EDIM; ++e) acc[rr][e] = 0.f;
    float psum[2] = {0.f, 0.f};

    #pragma unroll 2
    for (int p = 0; p < 64; ++p) {
        const unsigned int* rec = &sKV[(w * 64 + p) * 24];
        uint4 R0 = *reinterpret_cast<const uint4*>(&rec[0]);
        uint4 R1 = *reinterpret_cast<const uint4*>(&rec[4]);
        uint4 R2 = *reinterpret_cast<const uint4*>(&rec[8]);
        uint4 R3 = *reinterpret_cast<const uint4*>(&rec[12]);
        uint4 R4 = *reinterpret_cast<const uint4*>(&rec[16]);
        uint4 R5 = *reinterpret_cast<const uint4*>(&rec[20]);
        h2 km0[6] = {u2h(R3.x), u2h(R3.y), u2h(R3.z), u2h(R3.w), u2h(R4.x), u2h(R4.y)};
        h2 km1[6] = {u2h(R4.z), u2h(R4.w), u2h(R5.x), u2h(R5.y), u2h(R5.z), u2h(R5.w)};
        h2 v2[12] = {u2h(R0.x), u2h(R0.y), u2h(R0.z), u2h(R0.w),
                     u2h(R1.x), u2h(R1.y), u2h(R1.z), u2h(R1.w),
                     u2h(R2.x), u2h(R2.y), u2h(R2.z), u2h(R2.w)};
        h2 p2[2];
        #pragma unroll
        for (int rr = 0; rr < 2; ++rr) {
            float s0 = 0.f, s1 = 0.f;
            #pragma unroll
            for (int j = 0; j < 6; ++j) s0 = fd2(q2[rr][j], km0[j], s0);
            #pragma unroll
            for (int j = 0; j < 6; ++j) s1 = fd2(q2[rr][j], km1[j], s1);
            float pe0 = ex2_(s0 - M2v[rr]);
            float pe1 = ex2_(s1 - M2v[rr]);
            psum[rr] += pe0 + pe1;
            p2[rr] = pk16(pe0, pe1);
        }
        #pragma unroll
        for (int e = 0; e < EDIM; ++e) {
            acc[0][e] = fd2(p2[0], v2[e], acc[0][e]);
            acc[1][e] = fd2(p2[1], v2[e], acc[1][e]);
        }
    }

    // ---- per-row epilogue: out-proj + LN1 + MLP + LN2 -> z into sX ----
    #pragma unroll
    for (int rr = 0; rr < 2; ++rr) {
        const int row = ln + 64 * rr;
        const float inv = rcp_(fmaxf(psum[rr], 1e-35f));
        f2 at[6];
        #pragma unroll
        for (int j = 0; j < 6; ++j) {
            at[j].x = acc[rr][2*j]   * inv;
            at[j].y = acc[rr][2*j+1] * inv;
        }
        // re-read this row's x from the staged tile
        float4 xa = sX[row * XSLOT + w * 3 + 0];
        float4 xb = sX[row * XSLOT + w * 3 + 1];
        float4 xc = sX[row * XSLOT + w * 3 + 2];
        f2 xr[6] = {lo2(xa), hi2(xa), lo2(xb), hi2(xb), lo2(xc), hi2(xc)};

        f2 r[6];
        #pragma unroll
        for (int f = 0; f < EDIM; f += 2) {
            float a0 = ob[f]     + dot12p(ow + f * EDIM,       at);
            float a1 = ob[f + 1] + dot12p(ow + (f + 1) * EDIM, at);
            f2 tr; tr.x = a0; tr.y = a1;
            r[f >> 1] = xr[f >> 1] + tr;
        }
        f2 sm = r[0] + r[1] + r[2] + r[3] + r[4] + r[5];
        float mu = (sm.x + sm.y) * (1.0f / 12.0f);
        f2 mub; mub.x = mu; mub.y = mu;
        f2 vs = {0.f, 0.f};
        #pragma unroll
        for (int j = 0; j < 6; ++j) { f2 d = r[j] - mub; vs = pf(d, d, vs); }
        float rs = rsq_((vs.x + vs.y) * (1.0f / 12.0f) + 1e-5f);
        f2 rsb; rsb.x = rs; rsb.y = rs;
        const f2* g1p  = reinterpret_cast<const f2*>(g1);
        const f2* be1p = reinterpret_cast<const f2*>(be1);
        f2 y[6];
        #pragma unroll
        for (int j = 0; j < 6; ++j)
            y[j] = pf((r[j] - mub) * rsb, g1p[j], be1p[j]);

        f2 h1[16];
        #pragma unroll
        for (int h = 0; h < HDIM; h += 2) {
            float a0 = tanh_(b1[h]     + dot12p(w1 + h * EDIM,       y));
            float a1 = tanh_(b1[h + 1] + dot12p(w1 + (h + 1) * EDIM, y));
            f2 th; th.x = a0; th.y = a1;
            h1[h >> 1] = th;
        }
        f2 h2v[16];
        #pragma unroll
        for (int g = 0; g < HDIM; g += 2) {
            float a0 = tanh_(b2[g]     + dot32p(w2 + g * HDIM,       h1));
            float a1 = tanh_(b2[g + 1] + dot32p(w2 + (g + 1) * HDIM, h1));
            f2 th; th.x = a0; th.y = a1;
            h2v[g >> 1] = th;
        }
        f2 r2[6];
        #pragma unroll
        for (int e = 0; e < EDIM; e += 2) {
            float a0 = tanh_(b3[e]     + dot32p(w3 + e * HDIM,       h2v));
            float a1 = tanh_(b3[e + 1] + dot32p(w3 + (e + 1) * HDIM, h2v));
            f2 th; th.x = a0; th.y = a1;
            r2[e >> 1] = y[e >> 1] + th;
        }

        f2 sm2 = r2[0] + r2[1] + r2[2] + r2[3] + r2[4] + r2[5];
        float mu2 = (sm2.x + sm2.y) * (1.0f / 12.0f);
        f2 mub2; mub2.x = mu2; mub2.y = mu2;
        f2 vs2 = {0.f, 0.f};
        #pragma unroll
        for (int j = 0; j < 6; ++j) { f2 d = r2[j] - mub2; vs2 = pf(d, d, vs2); }
        float rs2 = rsq_((vs2.x + vs2.y) * (1.0f / 12.0f) + 1e-5f);
        f2 rsb2; rsb2.x = rs2; rsb2.y = rs2;
        const f2* g2p  = reinterpret_cast<const f2*>(g2);
        const f2* be2p = reinterpret_cast<const f2*>(be2);
        f2 z[6];
        #pragma unroll
        for (int j = 0; j < 6; ++j)
            z[j] = pf((r2[j] - mub2) * rsb2, g2p[j], be2p[j]);

        const int base = row * XSLOT + w * 3;
        sX[base + 0] = make_float4(z[0].x, z[0].y, z[1].x, z[1].y);
        sX[base + 1] = make_float4(z[2].x, z[2].y, z[3].x, z[3].y);
        sX[base + 2] = make_float4(z[4].x, z[4].y, z[5].x, z[5].y);
    }

    __syncthreads();

    // ---- cooperative coalesced store ----
    float4* og = reinterpret_cast<float4*>(out);
    #pragma unroll
    for (int j = 0; j < 6; ++j) {
        int i = t + 256 * j;
        int l = i / 12, r = i - l * 12;
        og[(size_t)l * (NDIM * 3) + n0 * 3 + r] = sX[l * XSLOT + r];
    }
}

extern "C" void kernel_launch(void* const* d_in, const int* in_sizes, int n_in,
                              void* d_out, int out_size, void* d_ws, size_t ws_size,
                              hipStream_t stream) {
    const float* x   = (const float*)d_in[0];
    const float* inw = (const float*)d_in[1];
    const float* inb = (const float*)d_in[2];
    const float* ow  = (const float*)d_in[3];
    const float* ob  = (const float*)d_in[4];
    const float* w1  = (const float*)d_in[5];
    const float* b1  = (const float*)d_in[6];
    const float* w2  = (const float*)d_in[7];
    const float* b2  = (const float*)d_in[8];
    const float* w3  = (const float*)d_in[9];
    const float* b3  = (const float*)d_in[10];
    const float* g1  = (const float*)d_in[11];
    const float* be1 = (const float*)d_in[12];
    const float* g2  = (const float*)d_in[13];
    const float* be2 = (const float*)d_in[14];
    float* out = (float*)d_out;

    encoder_fused<<<dim3(NDIM / NT), dim3(256), 0, stream>>>(
        x, inw, inb, ow, ob, w1, b1, w2, b2, w3, b3, g1, be1, g2, be2, out);
}

// Round 7
// 180.530 us; speedup vs baseline: 1.1427x; 1.1166x over previous
//
#include <hip/hip_runtime.h>

#define NDIM 4096
#define LDIM 128
#define EDIM 12
#define HDIM 32
#define NT   4          // n per block, one per wave; no cross-wave sharing
#define NREG 11776      // per-n LDS region bytes
#define OFF_Q  0        // 128 rows x 16 f16 = 4096 B   (later overlaid by sO)
#define OFF_K  4096     // 128 rows x 16 f16 = 4096 B   (overlaid by sO)
#define OFF_VT 8192     // 12 feats x 128 keys f16 = 3072 B (partially overlaid)
#define OFF_PS 11264    // 128 f32 = 512 B (NOT overlaid)
#define OFF_O  0        // 128 rows x 20 f32 = 10240 B, overlays Q/K/VT

typedef float    f2  __attribute__((ext_vector_type(2)));
typedef float    f4v __attribute__((ext_vector_type(4)));
typedef _Float16 h2  __attribute__((ext_vector_type(2)));
typedef _Float16 h4  __attribute__((ext_vector_type(4)));

#ifndef __has_builtin
#define __has_builtin(x) 0
#endif

__device__ __forceinline__ float ex2_(float v) {
#if __has_builtin(__builtin_amdgcn_exp2f)
    return __builtin_amdgcn_exp2f(v);
#else
    return exp2f(v);
#endif
}
__device__ __forceinline__ float rcp_(float v) {
#if __has_builtin(__builtin_amdgcn_rcpf)
    return __builtin_amdgcn_rcpf(v);
#else
    return 1.0f / v;
#endif
}
__device__ __forceinline__ float rsq_(float v) {
#if __has_builtin(__builtin_amdgcn_rsqf)
    return __builtin_amdgcn_rsqf(v);
#else
    return rsqrtf(v);
#endif
}
// tanh(v) = 1 - 2/(e^{2v}+1)
__device__ __forceinline__ float tanh_(float v) {
    float t = ex2_(v * 2.8853900817779268f);
    return 1.0f - 2.0f * rcp_(t + 1.0f);
}

__device__ __forceinline__ f2 lo2(float4 v) { f2 r; r.x = v.x; r.y = v.y; return r; }
__device__ __forceinline__ f2 hi2(float4 v) { f2 r; r.x = v.z; r.y = v.w; return r; }
__device__ __forceinline__ f2 pf(f2 a, f2 b, f2 c) { return __builtin_elementwise_fma(a, b, c); }

// f32 pair -> packed f16
__device__ __forceinline__ h2 pk16(float a, float b) {
#if __has_builtin(__builtin_amdgcn_cvt_pkrtz)
    return __builtin_bit_cast(h2, __builtin_amdgcn_cvt_pkrtz(a, b));
#else
    h2 r; r.x = (_Float16)a; r.y = (_Float16)b; return r;
#endif
}
__device__ __forceinline__ unsigned int h2u(h2 a) { return __builtin_bit_cast(unsigned int, a); }

__device__ __forceinline__ f4v mfma16(h4 a, h4 b, f4v c) {
    return __builtin_amdgcn_mfma_f32_16x16x16f16(a, b, c, 0, 0, 0);
}

// dot(12-elem weight row (global, uniform -> s_load), f2[6]) via packed fma
__device__ __forceinline__ float dot12p(const float* __restrict__ w, const f2* v) {
    const float4* w4 = reinterpret_cast<const float4*>(w);
    float4 a = w4[0], b = w4[1], c = w4[2];
    f2 s = v[0] * lo2(a);
    s = pf(v[1], hi2(a), s);
    s = pf(v[2], lo2(b), s);
    s = pf(v[3], hi2(b), s);
    s = pf(v[4], lo2(c), s);
    s = pf(v[5], hi2(c), s);
    return s.x + s.y;
}
__device__ __forceinline__ float dot32p(const float* __restrict__ w, const f2* v) {
    const float4* w4 = reinterpret_cast<const float4*>(w);
    f2 s = {0.f, 0.f};
    #pragma unroll
    for (int c = 0; c < 8; ++c) {
        float4 t = w4[c];
        s = pf(v[2*c],   lo2(t), s);
        s = pf(v[2*c+1], hi2(t), s);
    }
    return s.x + s.y;
}

__global__ __launch_bounds__(256, 3)
void encoder_fused(const float* __restrict__ x,
                   const float* __restrict__ inw, const float* __restrict__ inb,
                   const float* __restrict__ ow,  const float* __restrict__ ob,
                   const float* __restrict__ w1,  const float* __restrict__ b1,
                   const float* __restrict__ w2,  const float* __restrict__ b2,
                   const float* __restrict__ w3,  const float* __restrict__ b3,
                   const float* __restrict__ g1,  const float* __restrict__ be1,
                   const float* __restrict__ g2,  const float* __restrict__ be2,
                   float* __restrict__ out)
{
    const int t  = threadIdx.x;
    const int wv = t >> 6;          // wave id = n_local (wave-private region)
    const int l  = t & 63;          // lane; owns rows l and l+64
    const int n  = blockIdx.x * NT + wv;

    __shared__ __align__(16) unsigned char lds[NT * NREG];
    unsigned char* base = lds + wv * NREG;
    unsigned int*         sQu = (unsigned int*)(base + OFF_Q);
    unsigned int*         sKu = (unsigned int*)(base + OFF_K);
    unsigned short*       sVT = (unsigned short*)(base + OFF_VT);
    float*                sPS = (float*)(base + OFF_PS);
    float*                sO  = (float*)(base + OFF_O);
    const unsigned short* sQh = (const unsigned short*)(base + OFF_Q);
    const unsigned short* sKh = (const unsigned short*)(base + OFF_K);

    const float SCALE = 0.2886751345948129f;   // 1/sqrt(12)
    const float L2E   = 1.4426950408889634f;

    // ================= phase 1: QKV projection -> LDS (f16 frag layouts) ====
    float qq[2];
    float knmx = 0.f;
    #pragma unroll
    for (int rr = 0; rr < 2; ++rr) {
        const int row = l + 64 * rr;
        const float* xp = x + ((size_t)row * NDIM + n) * EDIM;
        float4 xa = *reinterpret_cast<const float4*>(xp);
        float4 xb = *reinterpret_cast<const float4*>(xp + 4);
        float4 xc = *reinterpret_cast<const float4*>(xp + 8);
        f2 xr[6] = {lo2(xa), hi2(xa), lo2(xb), hi2(xb), lo2(xc), hi2(xc)};

        // Q (scaled; L2E folded so MFMA yields s*log2(e) directly)
        float qs[EDIM]; float aq = 0.f;
        #pragma unroll
        for (int f = 0; f < EDIM; ++f) {
            float a = (inb[f] + dot12p(inw + f * EDIM, xr)) * SCALE;
            qs[f] = a; aq += a * a;
        }
        qq[rr] = aq;
        unsigned int qw0 = h2u(pk16(qs[0]*L2E,  qs[1]*L2E));
        unsigned int qw1 = h2u(pk16(qs[2]*L2E,  qs[3]*L2E));
        unsigned int qw2 = h2u(pk16(qs[4]*L2E,  qs[5]*L2E));
        unsigned int qw3 = h2u(pk16(qs[6]*L2E,  qs[7]*L2E));
        unsigned int qw4 = h2u(pk16(qs[8]*L2E,  qs[9]*L2E));
        unsigned int qw5 = h2u(pk16(qs[10]*L2E, qs[11]*L2E));
        *reinterpret_cast<uint4*>(sQu + row * 8)     = make_uint4(qw0, qw1, qw2, qw3);
        *reinterpret_cast<uint4*>(sQu + row * 8 + 4) = make_uint4(qw4, qw5, 0u, 0u);

        // K
        float kv[EDIM]; float kn = 0.f;
        #pragma unroll
        for (int f = 0; f < EDIM; ++f) {
            float a = inb[12 + f] + dot12p(inw + (12 + f) * EDIM, xr);
            kv[f] = a; kn += a * a;
        }
        knmx = fmaxf(knmx, kn);
        unsigned int kw0 = h2u(pk16(kv[0], kv[1]));
        unsigned int kw1 = h2u(pk16(kv[2], kv[3]));
        unsigned int kw2 = h2u(pk16(kv[4], kv[5]));
        unsigned int kw3 = h2u(pk16(kv[6], kv[7]));
        unsigned int kw4 = h2u(pk16(kv[8], kv[9]));
        unsigned int kw5 = h2u(pk16(kv[10], kv[11]));
        *reinterpret_cast<uint4*>(sKu + row * 8)     = make_uint4(kw0, kw1, kw2, kw3);
        *reinterpret_cast<uint4*>(sKu + row * 8 + 4) = make_uint4(kw4, kw5, 0u, 0u);

        // V, transposed: sVT[feat][key]
        #pragma unroll
        for (int f = 0; f < EDIM; ++f) {
            float a = inb[24 + f] + dot12p(inw + (24 + f) * EDIM, xr);
            sVT[f * LDIM + row] = __builtin_bit_cast(unsigned short, (_Float16)a);
        }
    }

    // Cauchy-Schwarz softmax bound (log2 domain), per owned row
    float mk = knmx;
    #pragma unroll
    for (int off = 32; off > 0; off >>= 1) mk = fmaxf(mk, __shfl_xor(mk, off));
    float M2r0 = sqrtf(qq[0] * mk) * L2E;
    float M2r1 = sqrtf(qq[1] * mk) * L2E;
    // gather per-query bounds into MFMA column layout: query = (l&15)+16*tt
    float m2t[8];
    #pragma unroll
    for (int tt = 0; tt < 8; ++tt) {
        int qrow = (l & 15) + 16 * tt;
        m2t[tt] = (tt < 4) ? __shfl(M2r0, qrow) : __shfl(M2r1, qrow - 64);
    }

    // ================= phase 2: attention via MFMA =========================
    const int fg = l >> 4;      // 0..3 : k-group
    const int fr = l & 15;      // fragment row/col
    h4 qf[8];
    #pragma unroll
    for (int tt = 0; tt < 8; ++tt)
        qf[tt] = *reinterpret_cast<const h4*>(sQh + (fr + 16 * tt) * 16 + 4 * fg);

    f4v oc[8];
    #pragma unroll
    for (int tt = 0; tt < 8; ++tt) oc[tt] = (f4v){0.f, 0.f, 0.f, 0.f};
    float psum[8] = {0.f,0.f,0.f,0.f,0.f,0.f,0.f,0.f};
    const int vfeat = fr < 12 ? fr : 11;   // cols 12..15 of D are never read

    #pragma unroll
    for (int u = 0; u < 8; ++u) {
        h4 kf = *reinterpret_cast<const h4*>(sKh + (fr + 16 * u) * 16 + 4 * fg);
        h4 vf = *reinterpret_cast<const h4*>(sVT + vfeat * LDIM + 16 * u + 4 * fg);
        #pragma unroll
        for (int tt = 0; tt < 8; ++tt) {
            // S^T tile: D[key][query] = K . Q^T  (C-layout == PV A-layout)
            f4v c = mfma16(kf, qf[tt], (f4v){0.f, 0.f, 0.f, 0.f});
            float p0 = ex2_(c[0] - m2t[tt]);
            float p1 = ex2_(c[1] - m2t[tt]);
            float p2 = ex2_(c[2] - m2t[tt]);
            float p3 = ex2_(c[3] - m2t[tt]);
            psum[tt] += (p0 + p1) + (p2 + p3);
            h2 pa = pk16(p0, p1), pb = pk16(p2, p3);
            h4 paf; paf.x = pa.x; paf.y = pa.y; paf.z = pb.x; paf.w = pb.y;
            oc[tt] = mfma16(paf, vf, oc[tt]);   // O[query][feat] accumulate
        }
    }

    // per-query softmax denominators -> LDS
    #pragma unroll
    for (int tt = 0; tt < 8; ++tt) {
        psum[tt] += __shfl_xor(psum[tt], 16);
        psum[tt] += __shfl_xor(psum[tt], 32);
    }
    if (fg == 0) {
        #pragma unroll
        for (int tt = 0; tt < 8; ++tt) sPS[fr + 16 * tt] = psum[tt];
    }
    // O (unnormalized) -> LDS row-major, pitch 20 f32 (overlays Q/K/VT)
    #pragma unroll
    for (int tt = 0; tt < 8; ++tt) {
        sO[(16 * tt + 4 * fg + 0) * 20 + fr] = oc[tt][0];
        sO[(16 * tt + 4 * fg + 1) * 20 + fr] = oc[tt][1];
        sO[(16 * tt + 4 * fg + 2) * 20 + fr] = oc[tt][2];
        sO[(16 * tt + 4 * fg + 3) * 20 + fr] = oc[tt][3];
    }

    // ================= phase 3: per-row epilogue ===========================
    #pragma unroll
    for (int rr = 0; rr < 2; ++rr) {
        const int row = l + 64 * rr;
        float4 c0 = *reinterpret_cast<const float4*>(sO + row * 20 + 0);
        float4 c1 = *reinterpret_cast<const float4*>(sO + row * 20 + 4);
        float4 c2 = *reinterpret_cast<const float4*>(sO + row * 20 + 8);
        const float inv = rcp_(fmaxf(sPS[row], 1e-35f));
        f2 iv; iv.x = inv; iv.y = inv;
        f2 at[6] = {lo2(c0)*iv, hi2(c0)*iv, lo2(c1)*iv, hi2(c1)*iv, lo2(c2)*iv, hi2(c2)*iv};

        // x re-read (block tile is L2-resident)
        const float* xp = x + ((size_t)row * NDIM + n) * EDIM;
        float4 xa = *reinterpret_cast<const float4*>(xp);
        float4 xb = *reinterpret_cast<const float4*>(xp + 4);
        float4 xc = *reinterpret_cast<const float4*>(xp + 8);
        f2 xr[6] = {lo2(xa), hi2(xa), lo2(xb), hi2(xb), lo2(xc), hi2(xc)};

        f2 r[6];
        #pragma unroll
        for (int f = 0; f < EDIM; f += 2) {
            float a0 = ob[f]     + dot12p(ow + f * EDIM,       at);
            float a1 = ob[f + 1] + dot12p(ow + (f + 1) * EDIM, at);
            f2 tr; tr.x = a0; tr.y = a1;
            r[f >> 1] = xr[f >> 1] + tr;
        }
        f2 sm = r[0] + r[1] + r[2] + r[3] + r[4] + r[5];
        float mu = (sm.x + sm.y) * (1.0f / 12.0f);
        f2 mub; mub.x = mu; mub.y = mu;
        f2 vs = {0.f, 0.f};
        #pragma unroll
        for (int j = 0; j < 6; ++j) { f2 d = r[j] - mub; vs = pf(d, d, vs); }
        float rs = rsq_((vs.x + vs.y) * (1.0f / 12.0f) + 1e-5f);
        f2 rsb; rsb.x = rs; rsb.y = rs;
        const f2* g1p  = reinterpret_cast<const f2*>(g1);
        const f2* be1p = reinterpret_cast<const f2*>(be1);
        f2 y[6];
        #pragma unroll
        for (int j = 0; j < 6; ++j)
            y[j] = pf((r[j] - mub) * rsb, g1p[j], be1p[j]);

        f2 h1[16];
        #pragma unroll
        for (int h = 0; h < HDIM; h += 2) {
            float a0 = tanh_(b1[h]     + dot12p(w1 + h * EDIM,       y));
            float a1 = tanh_(b1[h + 1] + dot12p(w1 + (h + 1) * EDIM, y));
            f2 th; th.x = a0; th.y = a1;
            h1[h >> 1] = th;
        }
        f2 h2v[16];
        #pragma unroll
        for (int g = 0; g < HDIM; g += 2) {
            float a0 = tanh_(b2[g]     + dot32p(w2 + g * HDIM,       h1));
            float a1 = tanh_(b2[g + 1] + dot32p(w2 + (g + 1) * HDIM, h1));
            f2 th; th.x = a0; th.y = a1;
            h2v[g >> 1] = th;
        }
        f2 r2[6];
        #pragma unroll
        for (int e = 0; e < EDIM; e += 2) {
            float a0 = tanh_(b3[e]     + dot32p(w3 + e * HDIM,       h2v));
            float a1 = tanh_(b3[e + 1] + dot32p(w3 + (e + 1) * HDIM, h2v));
            f2 th; th.x = a0; th.y = a1;
            r2[e >> 1] = y[e >> 1] + th;
        }

        f2 sm2 = r2[0] + r2[1] + r2[2] + r2[3] + r2[4] + r2[5];
        float mu2 = (sm2.x + sm2.y) * (1.0f / 12.0f);
        f2 mub2; mub2.x = mu2; mub2.y = mu2;
        f2 vs2 = {0.f, 0.f};
        #pragma unroll
        for (int j = 0; j < 6; ++j) { f2 d = r2[j] - mub2; vs2 = pf(d, d, vs2); }
        float rs2 = rsq_((vs2.x + vs2.y) * (1.0f / 12.0f) + 1e-5f);
        f2 rsb2; rsb2.x = rs2; rsb2.y = rs2;
        const f2* g2p  = reinterpret_cast<const f2*>(g2);
        const f2* be2p = reinterpret_cast<const f2*>(be2);
        f2 z[6];
        #pragma unroll
        for (int j = 0; j < 6; ++j)
            z[j] = pf((r2[j] - mub2) * rsb2, g2p[j], be2p[j]);

        float* orow = out + ((size_t)row * NDIM + n) * EDIM;
        *reinterpret_cast<float4*>(orow)     = make_float4(z[0].x, z[0].y, z[1].x, z[1].y);
        *reinterpret_cast<float4*>(orow + 4) = make_float4(z[2].x, z[2].y, z[3].x, z[3].y);
        *reinterpret_cast<float4*>(orow + 8) = make_float4(z[4].x, z[4].y, z[5].x, z[5].y);
    }
}

extern "C" void kernel_launch(void* const* d_in, const int* in_sizes, int n_in,
                              void* d_out, int out_size, void* d_ws, size_t ws_size,
                              hipStream_t stream) {
    const float* x   = (const float*)d_in[0];
    const float* inw = (const float*)d_in[1];
    const float* inb = (const float*)d_in[2];
    const float* ow  = (const float*)d_in[3];
    const float* ob  = (const float*)d_in[4];
    const float* w1  = (const float*)d_in[5];
    const float* b1  = (const float*)d_in[6];
    const float* w2  = (const float*)d_in[7];
    const float* b2  = (const float*)d_in[8];
    const float* w3  = (const float*)d_in[9];
    const float* b3  = (const float*)d_in[10];
    const float* g1  = (const float*)d_in[11];
    const float* be1 = (const float*)d_in[12];
    const float* g2  = (const float*)d_in[13];
    const float* be2 = (const float*)d_in[14];
    float* out = (float*)d_out;

    encoder_fused<<<dim3(NDIM / NT), dim3(256), 0, stream>>>(
        x, inw, inb, ow, ob, w1, b1, w2, b2, w3, b3, g1, be1, g2, be2, out);
}

// Round 8
// 82.745 us; speedup vs baseline: 2.4932x; 2.1818x over previous
//
#include <hip/hip_runtime.h>

#define NDIM 4096
#define LDIM 128
#define EDIM 12
#define HDIM 32

typedef float    f2 __attribute__((ext_vector_type(2)));
typedef _Float16 h2 __attribute__((ext_vector_type(2)));

#ifndef __has_builtin
#define __has_builtin(x) 0
#endif

__device__ __forceinline__ float ex2_(float v) {
#if __has_builtin(__builtin_amdgcn_exp2f)
    return __builtin_amdgcn_exp2f(v);
#else
    return exp2f(v);
#endif
}
__device__ __forceinline__ float rcp_(float v) {
#if __has_builtin(__builtin_amdgcn_rcpf)
    return __builtin_amdgcn_rcpf(v);
#else
    return 1.0f / v;
#endif
}
__device__ __forceinline__ float rsq_(float v) {
#if __has_builtin(__builtin_amdgcn_rsqf)
    return __builtin_amdgcn_rsqf(v);
#else
    return rsqrtf(v);
#endif
}
// tanh(v) = 1 - 2/(e^{2v}+1)
__device__ __forceinline__ float tanh_(float v) {
    float t = ex2_(v * 2.8853900817779268f);
    return 1.0f - 2.0f * rcp_(t + 1.0f);
}

__device__ __forceinline__ f2 lo2(float4 v) { f2 r; r.x = v.x; r.y = v.y; return r; }
__device__ __forceinline__ f2 hi2(float4 v) { f2 r; r.x = v.z; r.y = v.w; return r; }
__device__ __forceinline__ f2 pf(f2 a, f2 b, f2 c) { return __builtin_elementwise_fma(a, b, c); }

// f32 pair -> packed f16 (single v_cvt_pkrtz)
__device__ __forceinline__ h2 pk16(float a, float b) {
#if __has_builtin(__builtin_amdgcn_cvt_pkrtz)
    return __builtin_bit_cast(h2, __builtin_amdgcn_cvt_pkrtz(a, b));
#else
    h2 r; r.x = (_Float16)a; r.y = (_Float16)b; return r;
#endif
}
// v_dot2_f32_f16: a.x*b.x + a.y*b.y + c
__device__ __forceinline__ float fd2(h2 a, h2 b, float c) {
#if __has_builtin(__builtin_amdgcn_fdot2)
    return __builtin_amdgcn_fdot2(a, b, c, false);
#else
    return (float)a.x * (float)b.x + (float)a.y * (float)b.y + c;
#endif
}
__device__ __forceinline__ unsigned int h2u(h2 a) { return __builtin_bit_cast(unsigned int, a); }
__device__ __forceinline__ h2 u2h(unsigned int a) { return __builtin_bit_cast(h2, a); }

// dot(12-elem weight row (global, uniform -> s_load), f2[6]) via packed fma
__device__ __forceinline__ float dot12p(const float* __restrict__ w, const f2* v) {
    const float4* w4 = reinterpret_cast<const float4*>(w);
    float4 a = w4[0], b = w4[1], c = w4[2];
    f2 s = v[0] * lo2(a);
    s = pf(v[1], hi2(a), s);
    s = pf(v[2], lo2(b), s);
    s = pf(v[3], hi2(b), s);
    s = pf(v[4], lo2(c), s);
    s = pf(v[5], hi2(c), s);
    return s.x + s.y;
}
__device__ __forceinline__ float dot32p(const float* __restrict__ w, const f2* v) {
    const float4* w4 = reinterpret_cast<const float4*>(w);
    f2 s = {0.f, 0.f};
    #pragma unroll
    for (int c = 0; c < 8; ++c) {
        float4 t = w4[c];
        s = pf(v[2*c],   lo2(t), s);
        s = pf(v[2*c+1], hi2(t), s);
    }
    return s.x + s.y;
}

__global__ __launch_bounds__(256, 4)
void encoder_fused(const float* __restrict__ x,
                   const float* __restrict__ inw, const float* __restrict__ inb,
                   const float* __restrict__ ow,  const float* __restrict__ ob,
                   const float* __restrict__ w1,  const float* __restrict__ b1,
                   const float* __restrict__ w2,  const float* __restrict__ b2,
                   const float* __restrict__ w3,  const float* __restrict__ b3,
                   const float* __restrict__ g1,  const float* __restrict__ be1,
                   const float* __restrict__ g2,  const float* __restrict__ be2,
                   float* __restrict__ out)
{
    const int tid = threadIdx.x;
    const int p   = tid >> 7;         // n within block (0..1)
    const int l   = tid & 127;        // query row, ONE per thread (no-spill rule)
    const int wv2 = (tid >> 6) & 1;   // wave within the n
    const int ln  = tid & 63;
    const int n   = blockIdx.x * 2 + p;

    // per m-pair 96B record: words 0-11 V interleaved (v2[e]=(v_m0[e],v_m1[e])),
    // words 12-17 K_m0 (f16 pairs along e), words 18-23 K_m1
    __shared__ unsigned int sKV[2][64][24];   // 12.3 KB
    __shared__ float        sMk[2][2];

    const float SCALE = 0.2886751345948129f;   // 1/sqrt(12)
    const float L2E   = 1.4426950408889634f;

    // ---- load this thread's x row ----
    const float* xp = x + ((size_t)l * NDIM + n) * EDIM;
    float4 xa = *reinterpret_cast<const float4*>(xp);
    float4 xb = *reinterpret_cast<const float4*>(xp + 4);
    float4 xc = *reinterpret_cast<const float4*>(xp + 8);
    f2 xr[6] = {lo2(xa), hi2(xa), lo2(xb), hi2(xb), lo2(xc), hi2(xc)};

    // ---- QKV projection (weights via scalar loads) ----
    h2 q2[6];                 // q * SCALE * L2E, packed f16
    float qq = 0.f;
    #pragma unroll
    for (int f = 0; f < EDIM; f += 2) {
        float a0 = (inb[f]     + dot12p(inw + f * EDIM,       xr)) * SCALE;
        float a1 = (inb[f + 1] + dot12p(inw + (f + 1) * EDIM, xr)) * SCALE;
        qq += a0 * a0 + a1 * a1;
        q2[f >> 1] = pk16(a0 * L2E, a1 * L2E);
    }
    float kv[EDIM];
    float kn = 0.f;
    #pragma unroll
    for (int f = 0; f < EDIM; ++f) {
        float a = inb[12 + f] + dot12p(inw + (12 + f) * EDIM, xr);
        kv[f] = a; kn += a * a;
    }
    unsigned int kw[6];
    #pragma unroll
    for (int j = 0; j < 6; ++j) kw[j] = h2u(pk16(kv[2*j], kv[2*j+1]));

    #pragma unroll
    for (int f = 0; f < EDIM; ++f)
        kv[f] = inb[24 + f] + dot12p(inw + (24 + f) * EDIM, xr);
    unsigned int vw[6], ov[6];
    #pragma unroll
    for (int j = 0; j < 6; ++j) vw[j] = h2u(pk16(kv[2*j], kv[2*j+1]));
    #pragma unroll
    for (int j = 0; j < 6; ++j) ov[j] = __shfl_xor(vw[j], 1);

    {
        unsigned int* rec = &sKV[p][l >> 1][0];
        if (!(l & 1)) {
            // even row = m0; neighbor = m1: interleave V across the pair
            unsigned int vi[12];
            #pragma unroll
            for (int j = 0; j < 6; ++j) {
                vi[2*j]   = (vw[j] & 0xffffu) | (ov[j] << 16);
                vi[2*j+1] = (vw[j] >> 16)     | (ov[j] & 0xffff0000u);
            }
            *reinterpret_cast<uint4*>(&rec[0])  = make_uint4(vi[0], vi[1], vi[2],  vi[3]);
            *reinterpret_cast<uint4*>(&rec[4])  = make_uint4(vi[4], vi[5], vi[6],  vi[7]);
            *reinterpret_cast<uint4*>(&rec[8])  = make_uint4(vi[8], vi[9], vi[10], vi[11]);
            *reinterpret_cast<uint4*>(&rec[12]) = make_uint4(kw[0], kw[1], kw[2], kw[3]);
            *reinterpret_cast<uint2*>(&rec[16]) = make_uint2(kw[4], kw[5]);
        } else {
            *reinterpret_cast<uint2*>(&rec[18]) = make_uint2(kw[0], kw[1]);
            *reinterpret_cast<uint2*>(&rec[20]) = make_uint2(kw[2], kw[3]);
            *reinterpret_cast<uint2*>(&rec[22]) = make_uint2(kw[4], kw[5]);
        }
    }

    // max ||k||^2 over this n's 128 rows: wave reduce + cross-wave LDS bounce
    float mk = kn;
    #pragma unroll
    for (int off = 32; off > 0; off >>= 1) mk = fmaxf(mk, __shfl_xor(mk, off));
    if (ln == 0) sMk[p][wv2] = mk;
    __syncthreads();
    // Cauchy-Schwarz bound in log2 domain: s - M2 <= ~0
    const float M2 = sqrtf(qq * fmaxf(sMk[p][0], sMk[p][1])) * L2E;

    // ---- single-pass attention: 6 broadcast b128 per m-PAIR ----
    float acc[EDIM] = {0,0,0,0,0,0,0,0,0,0,0,0};
    float psum = 0.f;

    #pragma unroll 2
    for (int pr = 0; pr < 64; ++pr) {
        const unsigned int* rec = &sKV[p][pr][0];
        uint4 R0 = *reinterpret_cast<const uint4*>(&rec[0]);
        uint4 R1 = *reinterpret_cast<const uint4*>(&rec[4]);
        uint4 R2 = *reinterpret_cast<const uint4*>(&rec[8]);
        uint4 R3 = *reinterpret_cast<const uint4*>(&rec[12]);
        uint4 R4 = *reinterpret_cast<const uint4*>(&rec[16]);
        uint4 R5 = *reinterpret_cast<const uint4*>(&rec[20]);
        float s0 = 0.f, s1 = 0.f;
        s0 = fd2(q2[0], u2h(R3.x), s0);
        s0 = fd2(q2[1], u2h(R3.y), s0);
        s0 = fd2(q2[2], u2h(R3.z), s0);
        s0 = fd2(q2[3], u2h(R3.w), s0);
        s0 = fd2(q2[4], u2h(R4.x), s0);
        s0 = fd2(q2[5], u2h(R4.y), s0);
        s1 = fd2(q2[0], u2h(R4.z), s1);
        s1 = fd2(q2[1], u2h(R4.w), s1);
        s1 = fd2(q2[2], u2h(R5.x), s1);
        s1 = fd2(q2[3], u2h(R5.y), s1);
        s1 = fd2(q2[4], u2h(R5.z), s1);
        s1 = fd2(q2[5], u2h(R5.w), s1);
        float pe0 = ex2_(s0 - M2);
        float pe1 = ex2_(s1 - M2);
        psum += pe0 + pe1;
        h2 pp = pk16(pe0, pe1);
        acc[0]  = fd2(pp, u2h(R0.x), acc[0]);
        acc[1]  = fd2(pp, u2h(R0.y), acc[1]);
        acc[2]  = fd2(pp, u2h(R0.z), acc[2]);
        acc[3]  = fd2(pp, u2h(R0.w), acc[3]);
        acc[4]  = fd2(pp, u2h(R1.x), acc[4]);
        acc[5]  = fd2(pp, u2h(R1.y), acc[5]);
        acc[6]  = fd2(pp, u2h(R1.z), acc[6]);
        acc[7]  = fd2(pp, u2h(R1.w), acc[7]);
        acc[8]  = fd2(pp, u2h(R2.x), acc[8]);
        acc[9]  = fd2(pp, u2h(R2.y), acc[9]);
        acc[10] = fd2(pp, u2h(R2.z), acc[10]);
        acc[11] = fd2(pp, u2h(R2.w), acc[11]);
    }

    const float inv = rcp_(fmaxf(psum, 1e-35f));
    f2 at[6];
    #pragma unroll
    for (int j = 0; j < 6; ++j) { at[j].x = acc[2*j] * inv; at[j].y = acc[2*j+1] * inv; }

    // ---- out projection + residual + LN1 ----
    f2 r[6];
    #pragma unroll
    for (int f = 0; f < EDIM; f += 2) {
        float a0 = ob[f]     + dot12p(ow + f * EDIM,       at);
        float a1 = ob[f + 1] + dot12p(ow + (f + 1) * EDIM, at);
        f2 t; t.x = a0; t.y = a1;
        r[f >> 1] = xr[f >> 1] + t;
    }
    f2 sm = r[0] + r[1] + r[2] + r[3] + r[4] + r[5];
    float mu = (sm.x + sm.y) * (1.0f / 12.0f);
    f2 mub; mub.x = mu; mub.y = mu;
    f2 vs = {0.f, 0.f};
    #pragma unroll
    for (int j = 0; j < 6; ++j) { f2 d = r[j] - mub; vs = pf(d, d, vs); }
    float rs = rsq_((vs.x + vs.y) * (1.0f / 12.0f) + 1e-5f);
    f2 rsb; rsb.x = rs; rsb.y = rs;
    const f2* g1p  = reinterpret_cast<const f2*>(g1);
    const f2* be1p = reinterpret_cast<const f2*>(be1);
    f2 y[6];
    #pragma unroll
    for (int j = 0; j < 6; ++j)
        y[j] = pf((r[j] - mub) * rsb, g1p[j], be1p[j]);

    // ---- MLP: 12 -> 32 -> 32 -> 12, tanh each (packed dots) ----
    f2 h1[16];
    #pragma unroll
    for (int h = 0; h < HDIM; h += 2) {
        float a0 = tanh_(b1[h]     + dot12p(w1 + h * EDIM,       y));
        float a1 = tanh_(b1[h + 1] + dot12p(w1 + (h + 1) * EDIM, y));
        f2 t; t.x = a0; t.y = a1;
        h1[h >> 1] = t;
    }
    f2 h2v[16];
    #pragma unroll
    for (int g = 0; g < HDIM; g += 2) {
        float a0 = tanh_(b2[g]     + dot32p(w2 + g * HDIM,       h1));
        float a1 = tanh_(b2[g + 1] + dot32p(w2 + (g + 1) * HDIM, h1));
        f2 t; t.x = a0; t.y = a1;
        h2v[g >> 1] = t;
    }
    f2 r2[6];
    #pragma unroll
    for (int e = 0; e < EDIM; e += 2) {
        float a0 = tanh_(b3[e]     + dot32p(w3 + e * HDIM,       h2v));
        float a1 = tanh_(b3[e + 1] + dot32p(w3 + (e + 1) * HDIM, h2v));
        f2 t; t.x = a0; t.y = a1;
        r2[e >> 1] = y[e >> 1] + t;
    }

    // ---- LN2 + store ----
    f2 sm2 = r2[0] + r2[1] + r2[2] + r2[3] + r2[4] + r2[5];
    float mu2 = (sm2.x + sm2.y) * (1.0f / 12.0f);
    f2 mub2; mub2.x = mu2; mub2.y = mu2;
    f2 vs2 = {0.f, 0.f};
    #pragma unroll
    for (int j = 0; j < 6; ++j) { f2 d = r2[j] - mub2; vs2 = pf(d, d, vs2); }
    float rs2 = rsq_((vs2.x + vs2.y) * (1.0f / 12.0f) + 1e-5f);
    f2 rsb2; rsb2.x = rs2; rsb2.y = rs2;
    const f2* g2p  = reinterpret_cast<const f2*>(g2);
    const f2* be2p = reinterpret_cast<const f2*>(be2);
    f2 z[6];
    #pragma unroll
    for (int j = 0; j < 6; ++j)
        z[j] = pf((r2[j] - mub2) * rsb2, g2p[j], be2p[j]);

    float* orow = out + ((size_t)l * NDIM + n) * EDIM;
    *reinterpret_cast<float4*>(orow)     = make_float4(z[0].x, z[0].y, z[1].x, z[1].y);
    *reinterpret_cast<float4*>(orow + 4) = make_float4(z[2].x, z[2].y, z[3].x, z[3].y);
    *reinterpret_cast<float4*>(orow + 8) = make_float4(z[4].x, z[4].y, z[5].x, z[5].y);
}

extern "C" void kernel_launch(void* const* d_in, const int* in_sizes, int n_in,
                              void* d_out, int out_size, void* d_ws, size_t ws_size,
                              hipStream_t stream) {
    const float* x   = (const float*)d_in[0];
    const float* inw = (const float*)d_in[1];
    const float* inb = (const float*)d_in[2];
    const float* ow  = (const float*)d_in[3];
    const float* ob  = (const float*)d_in[4];
    const float* w1  = (const float*)d_in[5];
    const float* b1  = (const float*)d_in[6];
    const float* w2  = (const float*)d_in[7];
    const float* b2  = (const float*)d_in[8];
    const float* w3  = (const float*)d_in[9];
    const float* b3  = (const float*)d_in[10];
    const float* g1  = (const float*)d_in[11];
    const float* be1 = (const float*)d_in[12];
    const float* g2  = (const float*)d_in[13];
    const float* be2 = (const float*)d_in[14];
    float* out = (float*)d_out;

    encoder_fused<<<dim3(NDIM / 2), dim3(256), 0, stream>>>(
        x, inw, inb, ow, ob, w1, b1, w2, b2, w3, b3, g1, be1, g2, be2, out);
}

// Round 9
// 65.129 us; speedup vs baseline: 3.1676x; 1.2705x over previous
//
#include <hip/hip_runtime.h>

#define NDIM 4096
#define LDIM 128
#define EDIM 12
#define HDIM 32

typedef float    f2  __attribute__((ext_vector_type(2)));
typedef float    f4v __attribute__((ext_vector_type(4)));
typedef _Float16 h2  __attribute__((ext_vector_type(2)));
typedef _Float16 h4  __attribute__((ext_vector_type(4)));

#ifndef __has_builtin
#define __has_builtin(x) 0
#endif

__device__ __forceinline__ float ex2_(float v) {
#if __has_builtin(__builtin_amdgcn_exp2f)
    return __builtin_amdgcn_exp2f(v);
#else
    return exp2f(v);
#endif
}
__device__ __forceinline__ float rcp_(float v) {
#if __has_builtin(__builtin_amdgcn_rcpf)
    return __builtin_amdgcn_rcpf(v);
#else
    return 1.0f / v;
#endif
}
__device__ __forceinline__ float rsq_(float v) {
#if __has_builtin(__builtin_amdgcn_rsqf)
    return __builtin_amdgcn_rsqf(v);
#else
    return rsqrtf(v);
#endif
}
// tanh(v) = 1 - 2/(e^{2v}+1)
__device__ __forceinline__ float tanh_(float v) {
    float t = ex2_(v * 2.8853900817779268f);
    return 1.0f - 2.0f * rcp_(t + 1.0f);
}

__device__ __forceinline__ f2 lo2(float4 v) { f2 r; r.x = v.x; r.y = v.y; return r; }
__device__ __forceinline__ f2 hi2(float4 v) { f2 r; r.x = v.z; r.y = v.w; return r; }
__device__ __forceinline__ f2 pf(f2 a, f2 b, f2 c) { return __builtin_elementwise_fma(a, b, c); }

// f32 pair -> packed f16 (single v_cvt_pkrtz)
__device__ __forceinline__ h2 pk16(float a, float b) {
#if __has_builtin(__builtin_amdgcn_cvt_pkrtz)
    return __builtin_bit_cast(h2, __builtin_amdgcn_cvt_pkrtz(a, b));
#else
    h2 r; r.x = (_Float16)a; r.y = (_Float16)b; return r;
#endif
}
__device__ __forceinline__ unsigned int h2u(h2 a) { return __builtin_bit_cast(unsigned int, a); }

__device__ __forceinline__ f4v mfma16(h4 a, h4 b, f4v c) {
    return __builtin_amdgcn_mfma_f32_16x16x16f16(a, b, c, 0, 0, 0);
}

// dot(12-elem weight row (global, uniform -> s_load), f2[6]) via packed fma
__device__ __forceinline__ float dot12p(const float* __restrict__ w, const f2* v) {
    const float4* w4 = reinterpret_cast<const float4*>(w);
    float4 a = w4[0], b = w4[1], c = w4[2];
    f2 s = v[0] * lo2(a);
    s = pf(v[1], hi2(a), s);
    s = pf(v[2], lo2(b), s);
    s = pf(v[3], hi2(b), s);
    s = pf(v[4], lo2(c), s);
    s = pf(v[5], hi2(c), s);
    return s.x + s.y;
}
__device__ __forceinline__ float dot32p(const float* __restrict__ w, const f2* v) {
    const float4* w4 = reinterpret_cast<const float4*>(w);
    f2 s = {0.f, 0.f};
    #pragma unroll
    for (int c = 0; c < 8; ++c) {
        float4 t = w4[c];
        s = pf(v[2*c],   lo2(t), s);
        s = pf(v[2*c+1], hi2(t), s);
    }
    return s.x + s.y;
}

__global__ __launch_bounds__(256, 3)
void encoder_fused(const float* __restrict__ x,
                   const float* __restrict__ inw, const float* __restrict__ inb,
                   const float* __restrict__ ow,  const float* __restrict__ ob,
                   const float* __restrict__ w1,  const float* __restrict__ b1,
                   const float* __restrict__ w2,  const float* __restrict__ b2,
                   const float* __restrict__ w3,  const float* __restrict__ b3,
                   const float* __restrict__ g1,  const float* __restrict__ be1,
                   const float* __restrict__ g2,  const float* __restrict__ be2,
                   float* __restrict__ out)
{
    const int tid  = threadIdx.x;
    const int p    = tid >> 7;         // n within block (0..1)
    const int l    = tid & 127;        // row, ONE per thread (no-spill rule)
    const int wv2  = (tid >> 6) & 1;   // wave within the n; owns rows 64*wv2..+63
    const int lane = tid & 63;
    const int fr   = lane & 15;        // fragment row/col
    const int fg   = lane >> 4;        // fragment k-group (0..3)
    const int n    = blockIdx.x * 2 + p;

    __shared__ unsigned int   sQu[2][LDIM][8];   // Q f16, frag rows (8 KB)
    __shared__ unsigned int   sKu[2][LDIM][8];   // K f16 (8 KB)
    __shared__ unsigned short sVT[2][EDIM][LDIM];// V^T f16 (6 KB)
    __shared__ float          sO [2][LDIM][16];  // unnormalized O (16 KB)
    __shared__ float          sPS[2][LDIM];      // softmax denominators (1 KB)
    __shared__ float          sMk[2][2];

    const float SCALE = 0.2886751345948129f;   // 1/sqrt(12)
    const float L2E   = 1.4426950408889634f;

    // ---- load this thread's x row ----
    const float* xp = x + ((size_t)l * NDIM + n) * EDIM;
    float4 xa = *reinterpret_cast<const float4*>(xp);
    float4 xb = *reinterpret_cast<const float4*>(xp + 4);
    float4 xc = *reinterpret_cast<const float4*>(xp + 8);
    f2 xr[6] = {lo2(xa), hi2(xa), lo2(xb), hi2(xb), lo2(xc), hi2(xc)};

    // ---- phase 1: QKV projection -> LDS (weights via scalar loads) ----
    float qs[EDIM]; float qq = 0.f;
    #pragma unroll
    for (int f = 0; f < EDIM; ++f) {
        float a = (inb[f] + dot12p(inw + f * EDIM, xr)) * SCALE;
        qs[f] = a; qq += a * a;
    }
    {
        unsigned int q0 = h2u(pk16(qs[0]*L2E,  qs[1]*L2E));
        unsigned int q1 = h2u(pk16(qs[2]*L2E,  qs[3]*L2E));
        unsigned int q2 = h2u(pk16(qs[4]*L2E,  qs[5]*L2E));
        unsigned int q3 = h2u(pk16(qs[6]*L2E,  qs[7]*L2E));
        unsigned int q4 = h2u(pk16(qs[8]*L2E,  qs[9]*L2E));
        unsigned int q5 = h2u(pk16(qs[10]*L2E, qs[11]*L2E));
        *reinterpret_cast<uint4*>(&sQu[p][l][0]) = make_uint4(q0, q1, q2, q3);
        *reinterpret_cast<uint4*>(&sQu[p][l][4]) = make_uint4(q4, q5, 0u, 0u);
    }
    float kv[EDIM]; float kn = 0.f;
    #pragma unroll
    for (int f = 0; f < EDIM; ++f) {
        float a = inb[12 + f] + dot12p(inw + (12 + f) * EDIM, xr);
        kv[f] = a; kn += a * a;
    }
    {
        unsigned int k0 = h2u(pk16(kv[0], kv[1]));
        unsigned int k1 = h2u(pk16(kv[2], kv[3]));
        unsigned int k2 = h2u(pk16(kv[4], kv[5]));
        unsigned int k3 = h2u(pk16(kv[6], kv[7]));
        unsigned int k4 = h2u(pk16(kv[8], kv[9]));
        unsigned int k5 = h2u(pk16(kv[10], kv[11]));
        *reinterpret_cast<uint4*>(&sKu[p][l][0]) = make_uint4(k0, k1, k2, k3);
        *reinterpret_cast<uint4*>(&sKu[p][l][4]) = make_uint4(k4, k5, 0u, 0u);
    }
    #pragma unroll
    for (int f = 0; f < EDIM; ++f) {
        float a = inb[24 + f] + dot12p(inw + (24 + f) * EDIM, xr);
        sVT[p][f][l] = __builtin_bit_cast(unsigned short, (_Float16)a);
    }

    // wave-local max ||k||^2, bounce across the n's two waves
    float mk = kn;
    #pragma unroll
    for (int off = 32; off > 0; off >>= 1) mk = fmaxf(mk, __shfl_xor(mk, off));
    if (lane == 0) sMk[p][wv2] = mk;
    __syncthreads();
    // Cauchy-Schwarz bound in log2 domain for THIS thread's query row
    const float M2 = sqrtf(qq * fmaxf(sMk[p][0], sMk[p][1])) * L2E;
    // gather bounds into MFMA tile-column order (queries of this wave)
    float m2t[4];
    #pragma unroll
    for (int ttl = 0; ttl < 4; ++ttl)
        m2t[ttl] = __shfl(M2, fr + 16 * ttl);   // row 64*wv2 + fr + 16*ttl

    // ---- phase 2: attention via MFMA (this wave's 64 queries, all keys) ----
    const unsigned short* sQh = (const unsigned short*)&sQu[p][0][0];
    const unsigned short* sKh = (const unsigned short*)&sKu[p][0][0];
    const int vfeat = fr < 12 ? fr : 11;   // D cols 12..15 never read

    h4 qf[4];
    #pragma unroll
    for (int ttl = 0; ttl < 4; ++ttl)
        qf[ttl] = *reinterpret_cast<const h4*>(sQh + (64*wv2 + 16*ttl + fr) * 16 + 4 * fg);

    f4v oc[4];
    #pragma unroll
    for (int ttl = 0; ttl < 4; ++ttl) oc[ttl] = (f4v){0.f, 0.f, 0.f, 0.f};
    float psum[4] = {0.f, 0.f, 0.f, 0.f};

    #pragma unroll
    for (int u = 0; u < 8; ++u) {
        h4 kf = *reinterpret_cast<const h4*>(sKh + (16*u + fr) * 16 + 4 * fg);
        h4 vf = *reinterpret_cast<const h4*>(&sVT[p][0][0] + vfeat * LDIM + 16*u + 4*fg);
        #pragma unroll
        for (int ttl = 0; ttl < 4; ++ttl) {
            // S^T tile: D[key][query] = K . Q^T  (C-layout == PV A-layout)
            f4v c = mfma16(kf, qf[ttl], (f4v){0.f, 0.f, 0.f, 0.f});
            float p0 = ex2_(c[0] - m2t[ttl]);
            float p1 = ex2_(c[1] - m2t[ttl]);
            float p2 = ex2_(c[2] - m2t[ttl]);
            float p3 = ex2_(c[3] - m2t[ttl]);
            psum[ttl] += (p0 + p1) + (p2 + p3);
            h2 pa = pk16(p0, p1), pb = pk16(p2, p3);
            h4 paf; paf.x = pa.x; paf.y = pa.y; paf.z = pb.x; paf.w = pb.y;
            oc[ttl] = mfma16(paf, vf, oc[ttl]);   // O[query][feat]
        }
    }

    // per-query denominators (reduce across fg groups) -> LDS (wave-local)
    #pragma unroll
    for (int ttl = 0; ttl < 4; ++ttl) {
        psum[ttl] += __shfl_xor(psum[ttl], 16);
        psum[ttl] += __shfl_xor(psum[ttl], 32);
    }
    if (fg == 0) {
        #pragma unroll
        for (int ttl = 0; ttl < 4; ++ttl)
            sPS[p][64*wv2 + 16*ttl + fr] = psum[ttl];
    }
    // O (unnormalized) -> LDS row-major (wave-local rows)
    #pragma unroll
    for (int ttl = 0; ttl < 4; ++ttl) {
        const int rb = 64*wv2 + 16*ttl + 4*fg;
        sO[p][rb + 0][fr] = oc[ttl][0];
        sO[p][rb + 1][fr] = oc[ttl][1];
        sO[p][rb + 2][fr] = oc[ttl][2];
        sO[p][rb + 3][fr] = oc[ttl][3];
    }

    // ---- phase 3: per-row epilogue (row l, same wave that wrote it) ----
    float4 c0 = *reinterpret_cast<const float4*>(&sO[p][l][0]);
    float4 c1 = *reinterpret_cast<const float4*>(&sO[p][l][4]);
    float4 c2 = *reinterpret_cast<const float4*>(&sO[p][l][8]);
    const float inv = rcp_(fmaxf(sPS[p][l], 1e-35f));
    f2 iv; iv.x = inv; iv.y = inv;
    f2 at[6] = {lo2(c0)*iv, hi2(c0)*iv, lo2(c1)*iv, hi2(c1)*iv, lo2(c2)*iv, hi2(c2)*iv};

    f2 r[6];
    #pragma unroll
    for (int f = 0; f < EDIM; f += 2) {
        float a0 = ob[f]     + dot12p(ow + f * EDIM,       at);
        float a1 = ob[f + 1] + dot12p(ow + (f + 1) * EDIM, at);
        f2 t; t.x = a0; t.y = a1;
        r[f >> 1] = xr[f >> 1] + t;
    }
    f2 sm = r[0] + r[1] + r[2] + r[3] + r[4] + r[5];
    float mu = (sm.x + sm.y) * (1.0f / 12.0f);
    f2 mub; mub.x = mu; mub.y = mu;
    f2 vs = {0.f, 0.f};
    #pragma unroll
    for (int j = 0; j < 6; ++j) { f2 d = r[j] - mub; vs = pf(d, d, vs); }
    float rs = rsq_((vs.x + vs.y) * (1.0f / 12.0f) + 1e-5f);
    f2 rsb; rsb.x = rs; rsb.y = rs;
    const f2* g1p  = reinterpret_cast<const f2*>(g1);
    const f2* be1p = reinterpret_cast<const f2*>(be1);
    f2 y[6];
    #pragma unroll
    for (int j = 0; j < 6; ++j)
        y[j] = pf((r[j] - mub) * rsb, g1p[j], be1p[j]);

    f2 h1[16];
    #pragma unroll
    for (int h = 0; h < HDIM; h += 2) {
        float a0 = tanh_(b1[h]     + dot12p(w1 + h * EDIM,       y));
        float a1 = tanh_(b1[h + 1] + dot12p(w1 + (h + 1) * EDIM, y));
        f2 t; t.x = a0; t.y = a1;
        h1[h >> 1] = t;
    }
    f2 h2v[16];
    #pragma unroll
    for (int g = 0; g < HDIM; g += 2) {
        float a0 = tanh_(b2[g]     + dot32p(w2 + g * HDIM,       h1));
        float a1 = tanh_(b2[g + 1] + dot32p(w2 + (g + 1) * HDIM, h1));
        f2 t; t.x = a0; t.y = a1;
        h2v[g >> 1] = t;
    }
    f2 r2[6];
    #pragma unroll
    for (int e = 0; e < EDIM; e += 2) {
        float a0 = tanh_(b3[e]     + dot32p(w3 + e * HDIM,       h2v));
        float a1 = tanh_(b3[e + 1] + dot32p(w3 + (e + 1) * HDIM, h2v));
        f2 t; t.x = a0; t.y = a1;
        r2[e >> 1] = y[e >> 1] + t;
    }

    f2 sm2 = r2[0] + r2[1] + r2[2] + r2[3] + r2[4] + r2[5];
    float mu2 = (sm2.x + sm2.y) * (1.0f / 12.0f);
    f2 mub2; mub2.x = mu2; mub2.y = mu2;
    f2 vs2 = {0.f, 0.f};
    #pragma unroll
    for (int j = 0; j < 6; ++j) { f2 d = r2[j] - mub2; vs2 = pf(d, d, vs2); }
    float rs2 = rsq_((vs2.x + vs2.y) * (1.0f / 12.0f) + 1e-5f);
    f2 rsb2; rsb2.x = rs2; rsb2.y = rs2;
    const f2* g2p  = reinterpret_cast<const f2*>(g2);
    const f2* be2p = reinterpret_cast<const f2*>(be2);
    f2 z[6];
    #pragma unroll
    for (int j = 0; j < 6; ++j)
        z[j] = pf((r2[j] - mub2) * rsb2, g2p[j], be2p[j]);

    float* orow = out + ((size_t)l * NDIM + n) * EDIM;
    *reinterpret_cast<float4*>(orow)     = make_float4(z[0].x, z[0].y, z[1].x, z[1].y);
    *reinterpret_cast<float4*>(orow + 4) = make_float4(z[2].x, z[2].y, z[3].x, z[3].y);
    *reinterpret_cast<float4*>(orow + 8) = make_float4(z[4].x, z[4].y, z[5].x, z[5].y);
}

extern "C" void kernel_launch(void* const* d_in, const int* in_sizes, int n_in,
                              void* d_out, int out_size, void* d_ws, size_t ws_size,
                              hipStream_t stream) {
    const float* x   = (const float*)d_in[0];
    const float* inw = (const float*)d_in[1];
    const float* inb = (const float*)d_in[2];
    const float* ow  = (const float*)d_in[3];
    const float* ob  = (const float*)d_in[4];
    const float* w1  = (const float*)d_in[5];
    const float* b1  = (const float*)d_in[6];
    const float* w2  = (const float*)d_in[7];
    const float* b2  = (const float*)d_in[8];
    const float* w3  = (const float*)d_in[9];
    const float* b3  = (const float*)d_in[10];
    const float* g1  = (const float*)d_in[11];
    const float* be1 = (const float*)d_in[12];
    const float* g2  = (const float*)d_in[13];
    const float* be2 = (const float*)d_in[14];
    float* out = (float*)d_out;

    encoder_fused<<<dim3(NDIM / 2), dim3(256), 0, stream>>>(
        x, inw, inb, ow, ob, w1, b1, w2, b2, w3, b3, g1, be1, g2, be2, out);
}

// Round 11
// 49.789 us; speedup vs baseline: 4.1435x; 1.3081x over previous
//
#include <hip/hip_runtime.h>

#define NDIM 4096
#define LDIM 128
#define EDIM 12
#define HDIM 32

typedef float    f2  __attribute__((ext_vector_type(2)));
typedef float    f4v __attribute__((ext_vector_type(4)));
typedef _Float16 h2  __attribute__((ext_vector_type(2)));
typedef _Float16 h4  __attribute__((ext_vector_type(4)));

#ifndef __has_builtin
#define __has_builtin(x) 0
#endif

__device__ __forceinline__ float ex2_(float v) {
#if __has_builtin(__builtin_amdgcn_exp2f)
    return __builtin_amdgcn_exp2f(v);
#else
    return exp2f(v);
#endif
}
__device__ __forceinline__ float rcp_(float v) {
#if __has_builtin(__builtin_amdgcn_rcpf)
    return __builtin_amdgcn_rcpf(v);
#else
    return 1.0f / v;
#endif
}
__device__ __forceinline__ float rsq_(float v) {
#if __has_builtin(__builtin_amdgcn_rsqf)
    return __builtin_amdgcn_rsqf(v);
#else
    return rsqrtf(v);
#endif
}
// tanh(v) = 1 - 2/(e^{2v}+1)
__device__ __forceinline__ float tanh_(float v) {
    float t = ex2_(v * 2.8853900817779268f);
    return 1.0f - 2.0f * rcp_(t + 1.0f);
}

__device__ __forceinline__ f2 lo2(float4 v) { f2 r; r.x = v.x; r.y = v.y; return r; }
__device__ __forceinline__ f2 hi2(float4 v) { f2 r; r.x = v.z; r.y = v.w; return r; }
__device__ __forceinline__ f2 pf(f2 a, f2 b, f2 c) { return __builtin_elementwise_fma(a, b, c); }

__device__ __forceinline__ h2 pk16(float a, float b) {
#if __has_builtin(__builtin_amdgcn_cvt_pkrtz)
    return __builtin_bit_cast(h2, __builtin_amdgcn_cvt_pkrtz(a, b));
#else
    h2 r; r.x = (_Float16)a; r.y = (_Float16)b; return r;
#endif
}
__device__ __forceinline__ unsigned int h2u(h2 a) { return __builtin_bit_cast(unsigned int, a); }
__device__ __forceinline__ h4 mkh4(h2 a, h2 b) {
    h4 r; r.x = a.x; r.y = a.y; r.z = b.x; r.w = b.y; return r;
}
__device__ __forceinline__ h4 cvt_h4(float4 w) { return mkh4(pk16(w.x, w.y), pk16(w.z, w.w)); }
__device__ __forceinline__ h4 h4z() {
    h4 r; r.x = (_Float16)0; r.y = (_Float16)0; r.z = (_Float16)0; r.w = (_Float16)0; return r;
}

__device__ __forceinline__ f4v mfma16(h4 a, h4 b, f4v c) {
    return __builtin_amdgcn_mfma_f32_16x16x16f16(a, b, c, 0, 0, 0);
}

// dot(12-elem weight row (global, uniform -> s_load), f2[6]) via packed fma
__device__ __forceinline__ float dot12p(const float* __restrict__ w, const f2* v) {
    const float4* w4 = reinterpret_cast<const float4*>(w);
    float4 a = w4[0], b = w4[1], c = w4[2];
    f2 s = v[0] * lo2(a);
    s = pf(v[1], hi2(a), s);
    s = pf(v[2], lo2(b), s);
    s = pf(v[3], hi2(b), s);
    s = pf(v[4], lo2(c), s);
    s = pf(v[5], hi2(c), s);
    return s.x + s.y;
}

__global__ __launch_bounds__(256, 3)
void encoder_fused(const float* __restrict__ x,
                   const float* __restrict__ inw, const float* __restrict__ inb,
                   const float* __restrict__ ow,  const float* __restrict__ ob,
                   const float* __restrict__ w1,  const float* __restrict__ b1,
                   const float* __restrict__ w2,  const float* __restrict__ b2,
                   const float* __restrict__ w3,  const float* __restrict__ b3,
                   const float* __restrict__ g1,  const float* __restrict__ be1,
                   const float* __restrict__ g2,  const float* __restrict__ be2,
                   float* __restrict__ out)
{
    const int tid  = threadIdx.x;
    const int p    = tid >> 7;         // n within block (0..1)
    const int l    = tid & 127;        // row, ONE per thread in phase 1
    const int wv2  = (tid >> 6) & 1;   // wave within the n; owns samples 64*wv2..+63
    const int lane = tid & 63;
    const int fr   = lane & 15;        // fragment col (sample/query slot)
    const int fg   = lane >> 4;        // fragment k-group (0..3)
    const int n    = blockIdx.x * 2 + p;
    const bool e_ok = (fg < 3);        // e = 4*fg+j < 12

    __shared__ unsigned int   sQu[2][LDIM][8];    // Q f16 frag rows, words 6,7 = 0
    __shared__ unsigned int   sKu[2][LDIM][8];    // K f16, words 6,7 = 0
    __shared__ unsigned short sVT[2][EDIM][132];  // V^T f16, padded
    __shared__ float          sXT[2][EDIM][129];  // x^T f32, padded
    __shared__ float          sM2[2][LDIM];       // per-row softmax bound (log2)
    __shared__ float          sMk[2][2];

    const float SCALE = 0.2886751345948129f;   // 1/sqrt(12)
    const float L2E   = 1.4426950408889634f;

    // ================= phase 1: per-row QKV projection -> LDS ==============
    {
        const float* xp = x + ((size_t)l * NDIM + n) * EDIM;
        float4 xa = *reinterpret_cast<const float4*>(xp);
        float4 xb = *reinterpret_cast<const float4*>(xp + 4);
        float4 xc = *reinterpret_cast<const float4*>(xp + 8);
        f2 xr[6] = {lo2(xa), hi2(xa), lo2(xb), hi2(xb), lo2(xc), hi2(xc)};
        // stage x^T for epilogue residual
        sXT[p][0][l]  = xa.x; sXT[p][1][l]  = xa.y; sXT[p][2][l]  = xa.z;
        sXT[p][3][l]  = xa.w; sXT[p][4][l]  = xb.x; sXT[p][5][l]  = xb.y;
        sXT[p][6][l]  = xb.z; sXT[p][7][l]  = xb.w; sXT[p][8][l]  = xc.x;
        sXT[p][9][l]  = xc.y; sXT[p][10][l] = xc.z; sXT[p][11][l] = xc.w;

        float qs[EDIM]; float qq = 0.f;
        #pragma unroll
        for (int f = 0; f < EDIM; ++f) {
            float a = (inb[f] + dot12p(inw + f * EDIM, xr)) * SCALE;
            qs[f] = a; qq += a * a;
        }
        unsigned int q0 = h2u(pk16(qs[0]*L2E,  qs[1]*L2E));
        unsigned int q1 = h2u(pk16(qs[2]*L2E,  qs[3]*L2E));
        unsigned int q2 = h2u(pk16(qs[4]*L2E,  qs[5]*L2E));
        unsigned int q3 = h2u(pk16(qs[6]*L2E,  qs[7]*L2E));
        unsigned int q4 = h2u(pk16(qs[8]*L2E,  qs[9]*L2E));
        unsigned int q5 = h2u(pk16(qs[10]*L2E, qs[11]*L2E));
        *reinterpret_cast<uint4*>(&sQu[p][l][0]) = make_uint4(q0, q1, q2, q3);
        *reinterpret_cast<uint4*>(&sQu[p][l][4]) = make_uint4(q4, q5, 0u, 0u);

        float kv[EDIM]; float kn = 0.f;
        #pragma unroll
        for (int f = 0; f < EDIM; ++f) {
            float a = inb[12 + f] + dot12p(inw + (12 + f) * EDIM, xr);
            kv[f] = a; kn += a * a;
        }
        unsigned int k0 = h2u(pk16(kv[0], kv[1]));
        unsigned int k1 = h2u(pk16(kv[2], kv[3]));
        unsigned int k2 = h2u(pk16(kv[4], kv[5]));
        unsigned int k3 = h2u(pk16(kv[6], kv[7]));
        unsigned int k4 = h2u(pk16(kv[8], kv[9]));
        unsigned int k5 = h2u(pk16(kv[10], kv[11]));
        *reinterpret_cast<uint4*>(&sKu[p][l][0]) = make_uint4(k0, k1, k2, k3);
        *reinterpret_cast<uint4*>(&sKu[p][l][4]) = make_uint4(k4, k5, 0u, 0u);

        #pragma unroll
        for (int f = 0; f < EDIM; ++f) {
            float a = inb[24 + f] + dot12p(inw + (24 + f) * EDIM, xr);
            sVT[p][f][l] = __builtin_bit_cast(unsigned short, (_Float16)a);
        }

        // max ||k||^2 over this n's 128 rows
        float mk = kn;
        #pragma unroll
        for (int off = 32; off > 0; off >>= 1) mk = fmaxf(mk, __shfl_xor(mk, off));
        if (lane == 0) sMk[p][wv2] = mk;
        __syncthreads();
        // Cauchy-Schwarz bound (log2 domain) for this row; dedicated stash
        sM2[p][l] = sqrtf(qq * fmaxf(sMk[p][0], sMk[p][1])) * L2E;
    }
    __syncthreads();   // K/V/Q + M2 all visible

    // ================= phase 2: attention via MFMA =========================
    const unsigned short* sQh = (const unsigned short*)&sQu[p][0][0];
    const unsigned short* sKh = (const unsigned short*)&sKu[p][0][0];

    float m2t[4];
    #pragma unroll
    for (int ttl = 0; ttl < 4; ++ttl)
        m2t[ttl] = sM2[p][64*wv2 + 16*ttl + fr];

    h4 qf[4];
    #pragma unroll
    for (int ttl = 0; ttl < 4; ++ttl)
        qf[ttl] = *reinterpret_cast<const h4*>(sQh + (64*wv2 + 16*ttl + fr) * 16 + 4 * fg);

    f4v oc[4];
    #pragma unroll
    for (int ttl = 0; ttl < 4; ++ttl) oc[ttl] = (f4v){0.f, 0.f, 0.f, 0.f};
    float psum[4] = {0.f, 0.f, 0.f, 0.f};

    #pragma unroll
    for (int u = 0; u < 8; ++u) {
        h4 kf = *reinterpret_cast<const h4*>(sKh + (16*u + fr) * 16 + 4 * fg);
        h4 vf = h4z();
        if (fr < 12)
            vf = *reinterpret_cast<const h4*>(&sVT[p][fr][16*u + 4*fg]);
        #pragma unroll
        for (int ttl = 0; ttl < 4; ++ttl) {
            // S^T tile: D[key][query] = K . Q^T
            f4v c = mfma16(kf, qf[ttl], (f4v){0.f, 0.f, 0.f, 0.f});
            float p0 = ex2_(c[0] - m2t[ttl]);
            float p1 = ex2_(c[1] - m2t[ttl]);
            float p2 = ex2_(c[2] - m2t[ttl]);
            float p3 = ex2_(c[3] - m2t[ttl]);
            psum[ttl] += (p0 + p1) + (p2 + p3);
            h4 paf = mkh4(pk16(p0, p1), pk16(p2, p3));
            oc[ttl] = mfma16(vf, paf, oc[ttl]);   // D = O^T[feat][sample]
        }
    }
    float inv[4];
    #pragma unroll
    for (int ttl = 0; ttl < 4; ++ttl) {
        psum[ttl] += __shfl_xor(psum[ttl], 16);
        psum[ttl] += __shfl_xor(psum[ttl], 32);
        inv[ttl] = rcp_(fmaxf(psum[ttl], 1e-35f));
    }

    // ============ epilogue constants: weight A-frags (f16) + biases ========
    const float4 F4Z = make_float4(0.f, 0.f, 0.f, 0.f);
    h4 OWf = h4z();
    if (fr < 12 && e_ok)
        OWf = cvt_h4(*reinterpret_cast<const float4*>(ow + fr * 12 + 4 * fg));
    h4 W1f[2] = {h4z(), h4z()};
    if (e_ok) {
        W1f[0] = cvt_h4(*reinterpret_cast<const float4*>(w1 + (fr     ) * 12 + 4 * fg));
        W1f[1] = cvt_h4(*reinterpret_cast<const float4*>(w1 + (fr + 16) * 12 + 4 * fg));
    }
    h4 W2f[2][2];
    #pragma unroll
    for (int gt = 0; gt < 2; ++gt)
        #pragma unroll
        for (int ks = 0; ks < 2; ++ks)
            W2f[gt][ks] = cvt_h4(*reinterpret_cast<const float4*>(
                w2 + (16*gt + fr) * 32 + 16*ks + 4*fg));
    h4 W3f[2] = {h4z(), h4z()};
    if (fr < 12) {
        W3f[0] = cvt_h4(*reinterpret_cast<const float4*>(w3 + fr * 32 +      4 * fg));
        W3f[1] = cvt_h4(*reinterpret_cast<const float4*>(w3 + fr * 32 + 16 + 4 * fg));
    }
    float4 ob4  = e_ok ? *reinterpret_cast<const float4*>(ob  + 4*fg) : F4Z;
    float4 b3v  = e_ok ? *reinterpret_cast<const float4*>(b3  + 4*fg) : F4Z;
    float4 g1v  = e_ok ? *reinterpret_cast<const float4*>(g1  + 4*fg) : F4Z;
    float4 be1v = e_ok ? *reinterpret_cast<const float4*>(be1 + 4*fg) : F4Z;
    float4 g2v  = e_ok ? *reinterpret_cast<const float4*>(g2  + 4*fg) : F4Z;
    float4 be2v = e_ok ? *reinterpret_cast<const float4*>(be2 + 4*fg) : F4Z;
    float4 b1t0 = *reinterpret_cast<const float4*>(b1 +      4*fg);
    float4 b1t1 = *reinterpret_cast<const float4*>(b1 + 16 + 4*fg);
    float4 b2t0 = *reinterpret_cast<const float4*>(b2 +      4*fg);
    float4 b2t1 = *reinterpret_cast<const float4*>(b2 + 16 + 4*fg);

    // ================= phase 3: fused MFMA epilogue, 4 sample-tiles ========
    #pragma unroll
    for (int st = 0; st < 4; ++st) {
        const int sample = 64*wv2 + 16*st + fr;
        // normalized O^T as B-frag (f16)
        h4 B0 = mkh4(pk16(oc[st][0]*inv[st], oc[st][1]*inv[st]),
                     pk16(oc[st][2]*inv[st], oc[st][3]*inv[st]));
        // out-proj: D0 = OW . O -> AttnProj^T[fout][sample]
        f4v D0 = mfma16(OWf, B0, (f4v){0.f, 0.f, 0.f, 0.f});
        float r0 = 0.f, r1 = 0.f, r2_ = 0.f, r3 = 0.f;
        if (e_ok) {
            r0 = D0[0] + ob4.x + sXT[p][4*fg + 0][sample];
            r1 = D0[1] + ob4.y + sXT[p][4*fg + 1][sample];
            r2_= D0[2] + ob4.z + sXT[p][4*fg + 2][sample];
            r3 = D0[3] + ob4.w + sXT[p][4*fg + 3][sample];
        }
        // LN1 across e: lane-local + cross-fg shfl reduce
        float s = (r0 + r1) + (r2_ + r3);
        s += __shfl_xor(s, 16); s += __shfl_xor(s, 32);
        float mu = s * (1.0f / 12.0f);
        float d0 = r0 - mu, d1 = r1 - mu, d2 = r2_ - mu, d3 = r3 - mu;
        float vv = e_ok ? ((d0*d0 + d1*d1) + (d2*d2 + d3*d3)) : 0.f;
        vv += __shfl_xor(vv, 16); vv += __shfl_xor(vv, 32);
        float rs = rsq_(vv * (1.0f / 12.0f) + 1e-5f);
        float y0 = 0.f, y1 = 0.f, y2 = 0.f, y3 = 0.f;
        if (e_ok) {
            y0 = d0 * rs * g1v.x + be1v.x;
            y1 = d1 * rs * g1v.y + be1v.y;
            y2 = d2 * rs * g1v.z + be1v.z;
            y3 = d3 * rs * g1v.w + be1v.w;
        }
        // GEMM1: H1^T = W1 . Y
        h4 yB = mkh4(pk16(y0, y1), pk16(y2, y3));
        f4v D1a = mfma16(W1f[0], yB, (f4v){0.f, 0.f, 0.f, 0.f});
        f4v D1b = mfma16(W1f[1], yB, (f4v){0.f, 0.f, 0.f, 0.f});
        h4 B1a = mkh4(pk16(tanh_(D1a[0] + b1t0.x), tanh_(D1a[1] + b1t0.y)),
                      pk16(tanh_(D1a[2] + b1t0.z), tanh_(D1a[3] + b1t0.w)));
        h4 B1b = mkh4(pk16(tanh_(D1b[0] + b1t1.x), tanh_(D1b[1] + b1t1.y)),
                      pk16(tanh_(D1b[2] + b1t1.z), tanh_(D1b[3] + b1t1.w)));
        // GEMM2: H2^T = W2 . TH1  (k = 32 -> 2 steps)
        f4v D2a = mfma16(W2f[0][1], B1b, mfma16(W2f[0][0], B1a, (f4v){0.f,0.f,0.f,0.f}));
        f4v D2b = mfma16(W2f[1][1], B1b, mfma16(W2f[1][0], B1a, (f4v){0.f,0.f,0.f,0.f}));
        h4 B2a = mkh4(pk16(tanh_(D2a[0] + b2t0.x), tanh_(D2a[1] + b2t0.y)),
                      pk16(tanh_(D2a[2] + b2t0.z), tanh_(D2a[3] + b2t0.w)));
        h4 B2b = mkh4(pk16(tanh_(D2b[0] + b2t1.x), tanh_(D2b[1] + b2t1.y)),
                      pk16(tanh_(D2b[2] + b2t1.z), tanh_(D2b[3] + b2t1.w)));
        // GEMM3: FF^T = W3 . TH2
        f4v D3 = mfma16(W3f[1], B2b, mfma16(W3f[0], B2a, (f4v){0.f,0.f,0.f,0.f}));
        float q0 = 0.f, q1 = 0.f, q2 = 0.f, q3 = 0.f;
        if (e_ok) {
            q0 = y0 + tanh_(D3[0] + b3v.x);
            q1 = y1 + tanh_(D3[1] + b3v.y);
            q2 = y2 + tanh_(D3[2] + b3v.z);
            q3 = y3 + tanh_(D3[3] + b3v.w);
        }
        // LN2
        float s2 = (q0 + q1) + (q2 + q3);
        s2 += __shfl_xor(s2, 16); s2 += __shfl_xor(s2, 32);
        float mu2 = s2 * (1.0f / 12.0f);
        float e0 = q0 - mu2, e1 = q1 - mu2, e2 = q2 - mu2, e3 = q3 - mu2;
        float vv2 = e_ok ? ((e0*e0 + e1*e1) + (e2*e2 + e3*e3)) : 0.f;
        vv2 += __shfl_xor(vv2, 16); vv2 += __shfl_xor(vv2, 32);
        float rs2 = rsq_(vv2 * (1.0f / 12.0f) + 1e-5f);
        if (e_ok) {
            float z0 = e0 * rs2 * g2v.x + be2v.x;
            float z1 = e1 * rs2 * g2v.y + be2v.y;
            float z2 = e2 * rs2 * g2v.z + be2v.z;
            float z3 = e3 * rs2 * g2v.w + be2v.w;
            float* op = out + ((size_t)sample * NDIM + n) * EDIM + 4 * fg;
            *reinterpret_cast<float4*>(op) = make_float4(z0, z1, z2, z3);
        }
    }
}

extern "C" void kernel_launch(void* const* d_in, const int* in_sizes, int n_in,
                              void* d_out, int out_size, void* d_ws, size_t ws_size,
                              hipStream_t stream) {
    const float* x   = (const float*)d_in[0];
    const float* inw = (const float*)d_in[1];
    const float* inb = (const float*)d_in[2];
    const float* ow  = (const float*)d_in[3];
    const float* ob  = (const float*)d_in[4];
    const float* w1  = (const float*)d_in[5];
    const float* b1  = (const float*)d_in[6];
    const float* w2  = (const float*)d_in[7];
    const float* b2  = (const float*)d_in[8];
    const float* w3  = (const float*)d_in[9];
    const float* b3  = (const float*)d_in[10];
    const float* g1  = (const float*)d_in[11];
    const float* be1 = (const float*)d_in[12];
    const float* g2  = (const float*)d_in[13];
    const float* be2 = (const float*)d_in[14];
    float* out = (float*)d_out;

    encoder_fused<<<dim3(NDIM / 2), dim3(256), 0, stream>>>(
        x, inw, inb, ow, ob, w1, b1, w2, b2, w3, b3, g1, be1, g2, be2, out);
}

// Round 12
// 45.408 us; speedup vs baseline: 4.5432x; 1.0965x over previous
//
#include <hip/hip_runtime.h>

#define NDIM 4096
#define LDIM 128
#define EDIM 12
#define HDIM 32
#define XPITCH 24   // u16 pitch for staged x rows (16 used; 48B, b128-aligned)

typedef float    f2  __attribute__((ext_vector_type(2)));
typedef float    f4v __attribute__((ext_vector_type(4)));
typedef _Float16 h2  __attribute__((ext_vector_type(2)));
typedef _Float16 h4  __attribute__((ext_vector_type(4)));

#ifndef __has_builtin
#define __has_builtin(x) 0
#endif

__device__ __forceinline__ float ex2_(float v) {
#if __has_builtin(__builtin_amdgcn_exp2f)
    return __builtin_amdgcn_exp2f(v);
#else
    return exp2f(v);
#endif
}
__device__ __forceinline__ float rcp_(float v) {
#if __has_builtin(__builtin_amdgcn_rcpf)
    return __builtin_amdgcn_rcpf(v);
#else
    return 1.0f / v;
#endif
}
__device__ __forceinline__ float rsq_(float v) {
#if __has_builtin(__builtin_amdgcn_rsqf)
    return __builtin_amdgcn_rsqf(v);
#else
    return rsqrtf(v);
#endif
}
// tanh(v) = 1 - 2/(e^{2v}+1)
__device__ __forceinline__ float tanh_(float v) {
    float t = ex2_(v * 2.8853900817779268f);
    return 1.0f - 2.0f * rcp_(t + 1.0f);
}

__device__ __forceinline__ h2 pk16(float a, float b) {
#if __has_builtin(__builtin_amdgcn_cvt_pkrtz)
    return __builtin_bit_cast(h2, __builtin_amdgcn_cvt_pkrtz(a, b));
#else
    h2 r; r.x = (_Float16)a; r.y = (_Float16)b; return r;
#endif
}
__device__ __forceinline__ unsigned int h2u(h2 a) { return __builtin_bit_cast(unsigned int, a); }
__device__ __forceinline__ h4 mkh4(h2 a, h2 b) {
    h4 r; r.x = a.x; r.y = a.y; r.z = b.x; r.w = b.y; return r;
}
__device__ __forceinline__ h4 cvt_h4(float4 w) { return mkh4(pk16(w.x, w.y), pk16(w.z, w.w)); }
__device__ __forceinline__ h4 h4z() {
    h4 r; r.x = (_Float16)0; r.y = (_Float16)0; r.z = (_Float16)0; r.w = (_Float16)0; return r;
}

__device__ __forceinline__ f4v mfma16(h4 a, h4 b, f4v c) {
    return __builtin_amdgcn_mfma_f32_16x16x16f16(a, b, c, 0, 0, 0);
}

__global__ __launch_bounds__(256, 3)
void encoder_fused(const float* __restrict__ x,
                   const float* __restrict__ inw, const float* __restrict__ inb,
                   const float* __restrict__ ow,  const float* __restrict__ ob,
                   const float* __restrict__ w1,  const float* __restrict__ b1,
                   const float* __restrict__ w2,  const float* __restrict__ b2,
                   const float* __restrict__ w3,  const float* __restrict__ b3,
                   const float* __restrict__ g1,  const float* __restrict__ be1,
                   const float* __restrict__ g2,  const float* __restrict__ be2,
                   float* __restrict__ out)
{
    const int tid  = threadIdx.x;
    const int p    = tid >> 7;         // n within block (0..1)
    const int l    = tid & 127;        // row staged by this thread
    const int wv2  = (tid >> 6) & 1;   // wave within the n; owns samples 64*wv2..+63
    const int lane = tid & 63;
    const int fr   = lane & 15;        // fragment row/col slot
    const int fg   = lane >> 4;        // fragment k-group (0..3)
    const int n    = blockIdx.x * 2 + p;
    const bool e_ok = (fg < 3);        // feat 4*fg+j < 12

    __shared__ unsigned short sXh[2][LDIM][XPITCH];  // x rows f16 (12 used + pad)  12.3 KB
    __shared__ unsigned short sVT[2][EDIM][132];     // V^T f16                      6.3 KB
    __shared__ h4             sKf[2][8][64];         // K A-frags per key tile       8.0 KB
    __shared__ float          sMk[2][2];

    const float SCALE = 0.2886751345948129f;   // 1/sqrt(12)
    const float L2E   = 1.4426950408889634f;
    const f4v   FZ    = (f4v){0.f, 0.f, 0.f, 0.f};

    // ================= stage x row l as f16 (B-frag friendly rows) =========
    {
        const float* xp = x + ((size_t)l * NDIM + n) * EDIM;
        float4 xa = *reinterpret_cast<const float4*>(xp);
        float4 xb = *reinterpret_cast<const float4*>(xp + 4);
        float4 xc = *reinterpret_cast<const float4*>(xp + 8);
        unsigned int u0 = h2u(pk16(xa.x, xa.y)), u1 = h2u(pk16(xa.z, xa.w));
        unsigned int u2 = h2u(pk16(xb.x, xb.y)), u3 = h2u(pk16(xb.z, xb.w));
        unsigned int u4 = h2u(pk16(xc.x, xc.y)), u5 = h2u(pk16(xc.z, xc.w));
        *reinterpret_cast<uint4*>(&sXh[p][l][0]) = make_uint4(u0, u1, u2, u3);
        *reinterpret_cast<uint4*>(&sXh[p][l][8]) = make_uint4(u4, u5, 0u, 0u);
    }

    // ---- projection weight A-frags (rows fr = fout, k = feat 4fg+j) ----
    h4 WQp = h4z(), WKp = h4z(), WVp = h4z();
    if (fr < 12 && e_ok) {
        WQp = cvt_h4(*reinterpret_cast<const float4*>(inw + (     fr) * 12 + 4 * fg));
        WKp = cvt_h4(*reinterpret_cast<const float4*>(inw + (12 + fr) * 12 + 4 * fg));
        WVp = cvt_h4(*reinterpret_cast<const float4*>(inw + (24 + fr) * 12 + 4 * fg));
    }
    const float4 F4Z = make_float4(0.f, 0.f, 0.f, 0.f);
    float4 bq4 = e_ok ? *reinterpret_cast<const float4*>(inb +      4 * fg) : F4Z;
    float4 bk4 = e_ok ? *reinterpret_cast<const float4*>(inb + 12 + 4 * fg) : F4Z;
    float4 bv4 = e_ok ? *reinterpret_cast<const float4*>(inb + 24 + 4 * fg) : F4Z;

    // ================= phase 1: QKV projection via MFMA ====================
    h4 qf[4];
    float qq[4];
    float mkw = 0.f;
    #pragma unroll
    for (int st = 0; st < 4; ++st) {
        const int srow = 64 * wv2 + 16 * st;   // base sample/key of this tile
        h4 xB = *reinterpret_cast<const h4*>(&sXh[p][srow + fr][4 * fg]);

        // Q: C-layout == B-frag for QK^T (q * SCALE, L2E folded at pack)
        f4v Dq = mfma16(WQp, xB, FZ);
        float q0 = (Dq[0] + bq4.x) * SCALE, q1 = (Dq[1] + bq4.y) * SCALE;
        float q2 = (Dq[2] + bq4.z) * SCALE, q3 = (Dq[3] + bq4.w) * SCALE;
        float aq = (q0*q0 + q1*q1) + (q2*q2 + q3*q3);
        aq += __shfl_xor(aq, 16); aq += __shfl_xor(aq, 32);
        qq[st] = aq;
        qf[st] = mkh4(pk16(q0 * L2E, q1 * L2E), pk16(q2 * L2E, q3 * L2E));

        // K: C-layout == A-frag for S^T; park in LDS for cross-wave reads
        f4v Dk = mfma16(WKp, xB, FZ);
        float k0 = Dk[0] + bk4.x, k1 = Dk[1] + bk4.y;
        float k2 = Dk[2] + bk4.z, k3 = Dk[3] + bk4.w;
        float kn = (k0*k0 + k1*k1) + (k2*k2 + k3*k3);
        kn += __shfl_xor(kn, 16); kn += __shfl_xor(kn, 32);
        kn = fmaxf(kn, __shfl_xor(kn, 1));
        kn = fmaxf(kn, __shfl_xor(kn, 2));
        kn = fmaxf(kn, __shfl_xor(kn, 4));
        kn = fmaxf(kn, __shfl_xor(kn, 8));
        mkw = fmaxf(mkw, kn);
        sKf[p][4 * wv2 + st][lane] = mkh4(pk16(k0, k1), pk16(k2, k3));

        // V: transpose into sVT[feat][key] for the PV A-frag
        f4v Dv = mfma16(WVp, xB, FZ);
        if (e_ok) {
            sVT[p][4*fg + 0][srow + fr] = __builtin_bit_cast(unsigned short, (_Float16)(Dv[0] + bv4.x));
            sVT[p][4*fg + 1][srow + fr] = __builtin_bit_cast(unsigned short, (_Float16)(Dv[1] + bv4.y));
            sVT[p][4*fg + 2][srow + fr] = __builtin_bit_cast(unsigned short, (_Float16)(Dv[2] + bv4.z));
            sVT[p][4*fg + 3][srow + fr] = __builtin_bit_cast(unsigned short, (_Float16)(Dv[3] + bv4.w));
        }
    }
    if (lane == 0) sMk[p][wv2] = mkw;
    __syncthreads();
    const float mkmax = fmaxf(sMk[p][0], sMk[p][1]);
    float m2t[4];
    #pragma unroll
    for (int st = 0; st < 4; ++st)
        m2t[st] = sqrtf(qq[st] * mkmax) * L2E;   // Cauchy-Schwarz bound, log2 domain

    // ================= phase 2: attention via MFMA =========================
    f4v oc[4];
    #pragma unroll
    for (int st = 0; st < 4; ++st) oc[st] = FZ;
    float psum[4] = {0.f, 0.f, 0.f, 0.f};

    #pragma unroll
    for (int u = 0; u < 8; ++u) {
        h4 kf = sKf[p][u][lane];
        h4 vf = h4z();
        if (fr < 12)
            vf = *reinterpret_cast<const h4*>(&sVT[p][fr][16 * u + 4 * fg]);
        #pragma unroll
        for (int st = 0; st < 4; ++st) {
            f4v c = mfma16(kf, qf[st], FZ);    // S^T[key][query]
            float p0 = ex2_(c[0] - m2t[st]);
            float p1 = ex2_(c[1] - m2t[st]);
            float p2 = ex2_(c[2] - m2t[st]);
            float p3 = ex2_(c[3] - m2t[st]);
            psum[st] += (p0 + p1) + (p2 + p3);
            h4 paf = mkh4(pk16(p0, p1), pk16(p2, p3));
            oc[st] = mfma16(vf, paf, oc[st]);  // O^T[feat][sample]
        }
    }
    float inv[4];
    #pragma unroll
    for (int st = 0; st < 4; ++st) {
        psum[st] += __shfl_xor(psum[st], 16);
        psum[st] += __shfl_xor(psum[st], 32);
        inv[st] = rcp_(fmaxf(psum[st], 1e-35f));
    }

    // ============ epilogue constants: weight A-frags (f16) + biases ========
    h4 OWf = h4z();
    if (fr < 12 && e_ok)
        OWf = cvt_h4(*reinterpret_cast<const float4*>(ow + fr * 12 + 4 * fg));
    h4 W1f[2] = {h4z(), h4z()};
    if (e_ok) {
        W1f[0] = cvt_h4(*reinterpret_cast<const float4*>(w1 + (fr     ) * 12 + 4 * fg));
        W1f[1] = cvt_h4(*reinterpret_cast<const float4*>(w1 + (fr + 16) * 12 + 4 * fg));
    }
    h4 W2f[2][2];
    #pragma unroll
    for (int gt = 0; gt < 2; ++gt)
        #pragma unroll
        for (int ks = 0; ks < 2; ++ks)
            W2f[gt][ks] = cvt_h4(*reinterpret_cast<const float4*>(
                w2 + (16*gt + fr) * 32 + 16*ks + 4*fg));
    h4 W3f[2] = {h4z(), h4z()};
    if (fr < 12) {
        W3f[0] = cvt_h4(*reinterpret_cast<const float4*>(w3 + fr * 32 +      4 * fg));
        W3f[1] = cvt_h4(*reinterpret_cast<const float4*>(w3 + fr * 32 + 16 + 4 * fg));
    }
    float4 ob4  = e_ok ? *reinterpret_cast<const float4*>(ob  + 4*fg) : F4Z;
    float4 b3v  = e_ok ? *reinterpret_cast<const float4*>(b3  + 4*fg) : F4Z;
    float4 g1v  = e_ok ? *reinterpret_cast<const float4*>(g1  + 4*fg) : F4Z;
    float4 be1v = e_ok ? *reinterpret_cast<const float4*>(be1 + 4*fg) : F4Z;
    float4 g2v  = e_ok ? *reinterpret_cast<const float4*>(g2  + 4*fg) : F4Z;
    float4 be2v = e_ok ? *reinterpret_cast<const float4*>(be2 + 4*fg) : F4Z;
    float4 b1t0 = *reinterpret_cast<const float4*>(b1 +      4*fg);
    float4 b1t1 = *reinterpret_cast<const float4*>(b1 + 16 + 4*fg);
    float4 b2t0 = *reinterpret_cast<const float4*>(b2 +      4*fg);
    float4 b2t1 = *reinterpret_cast<const float4*>(b2 + 16 + 4*fg);

    // ================= phase 3: fused MFMA epilogue ========================
    #pragma unroll
    for (int st = 0; st < 4; ++st) {
        const int sample = 64*wv2 + 16*st + fr;
        // normalized O^T as B-frag (f16)
        h4 B0 = mkh4(pk16(oc[st][0]*inv[st], oc[st][1]*inv[st]),
                     pk16(oc[st][2]*inv[st], oc[st][3]*inv[st]));
        // out-proj: D0 = OW . O -> AttnProj^T[fout][sample]
        f4v D0 = mfma16(OWf, B0, FZ);
        float r0 = 0.f, r1 = 0.f, r2_ = 0.f, r3 = 0.f;
        if (e_ok) {
            h4 xh4 = *reinterpret_cast<const h4*>(&sXh[p][sample][4 * fg]);
            r0 = D0[0] + ob4.x + (float)xh4.x;
            r1 = D0[1] + ob4.y + (float)xh4.y;
            r2_= D0[2] + ob4.z + (float)xh4.z;
            r3 = D0[3] + ob4.w + (float)xh4.w;
        }
        // LN1 across e
        float s = (r0 + r1) + (r2_ + r3);
        s += __shfl_xor(s, 16); s += __shfl_xor(s, 32);
        float mu = s * (1.0f / 12.0f);
        float d0 = r0 - mu, d1 = r1 - mu, d2 = r2_ - mu, d3 = r3 - mu;
        float vv = e_ok ? ((d0*d0 + d1*d1) + (d2*d2 + d3*d3)) : 0.f;
        vv += __shfl_xor(vv, 16); vv += __shfl_xor(vv, 32);
        float rs = rsq_(vv * (1.0f / 12.0f) + 1e-5f);
        float y0 = 0.f, y1 = 0.f, y2 = 0.f, y3 = 0.f;
        if (e_ok) {
            y0 = d0 * rs * g1v.x + be1v.x;
            y1 = d1 * rs * g1v.y + be1v.y;
            y2 = d2 * rs * g1v.z + be1v.z;
            y3 = d3 * rs * g1v.w + be1v.w;
        }
        // GEMM1: H1^T = W1 . Y
        h4 yB = mkh4(pk16(y0, y1), pk16(y2, y3));
        f4v D1a = mfma16(W1f[0], yB, FZ);
        f4v D1b = mfma16(W1f[1], yB, FZ);
        h4 B1a = mkh4(pk16(tanh_(D1a[0] + b1t0.x), tanh_(D1a[1] + b1t0.y)),
                      pk16(tanh_(D1a[2] + b1t0.z), tanh_(D1a[3] + b1t0.w)));
        h4 B1b = mkh4(pk16(tanh_(D1b[0] + b1t1.x), tanh_(D1b[1] + b1t1.y)),
                      pk16(tanh_(D1b[2] + b1t1.z), tanh_(D1b[3] + b1t1.w)));
        // GEMM2: H2^T = W2 . TH1 (k=32 -> 2 steps)
        f4v D2a = mfma16(W2f[0][1], B1b, mfma16(W2f[0][0], B1a, FZ));
        f4v D2b = mfma16(W2f[1][1], B1b, mfma16(W2f[1][0], B1a, FZ));
        h4 B2a = mkh4(pk16(tanh_(D2a[0] + b2t0.x), tanh_(D2a[1] + b2t0.y)),
                      pk16(tanh_(D2a[2] + b2t0.z), tanh_(D2a[3] + b2t0.w)));
        h4 B2b = mkh4(pk16(tanh_(D2b[0] + b2t1.x), tanh_(D2b[1] + b2t1.y)),
                      pk16(tanh_(D2b[2] + b2t1.z), tanh_(D2b[3] + b2t1.w)));
        // GEMM3: FF^T = W3 . TH2
        f4v D3 = mfma16(W3f[1], B2b, mfma16(W3f[0], B2a, FZ));
        float q0 = 0.f, q1 = 0.f, q2 = 0.f, q3 = 0.f;
        if (e_ok) {
            q0 = y0 + tanh_(D3[0] + b3v.x);
            q1 = y1 + tanh_(D3[1] + b3v.y);
            q2 = y2 + tanh_(D3[2] + b3v.z);
            q3 = y3 + tanh_(D3[3] + b3v.w);
        }
        // LN2
        float s2 = (q0 + q1) + (q2 + q3);
        s2 += __shfl_xor(s2, 16); s2 += __shfl_xor(s2, 32);
        float mu2 = s2 * (1.0f / 12.0f);
        float e0 = q0 - mu2, e1 = q1 - mu2, e2 = q2 - mu2, e3 = q3 - mu2;
        float vv2 = e_ok ? ((e0*e0 + e1*e1) + (e2*e2 + e3*e3)) : 0.f;
        vv2 += __shfl_xor(vv2, 16); vv2 += __shfl_xor(vv2, 32);
        float rs2 = rsq_(vv2 * (1.0f / 12.0f) + 1e-5f);
        if (e_ok) {
            float z0 = e0 * rs2 * g2v.x + be2v.x;
            float z1 = e1 * rs2 * g2v.y + be2v.y;
            float z2 = e2 * rs2 * g2v.z + be2v.z;
            float z3 = e3 * rs2 * g2v.w + be2v.w;
            float* op = out + ((size_t)sample * NDIM + n) * EDIM + 4 * fg;
            *reinterpret_cast<float4*>(op) = make_float4(z0, z1, z2, z3);
        }
    }
}

extern "C" void kernel_launch(void* const* d_in, const int* in_sizes, int n_in,
                              void* d_out, int out_size, void* d_ws, size_t ws_size,
                              hipStream_t stream) {
    const float* x   = (const float*)d_in[0];
    const float* inw = (const float*)d_in[1];
    const float* inb = (const float*)d_in[2];
    const float* ow  = (const float*)d_in[3];
    const float* ob  = (const float*)d_in[4];
    const float* w1  = (const float*)d_in[5];
    const float* b1  = (const float*)d_in[6];
    const float* w2  = (const float*)d_in[7];
    const float* b2  = (const float*)d_in[8];
    const float* w3  = (const float*)d_in[9];
    const float* b3  = (const float*)d_in[10];
    const float* g1  = (const float*)d_in[11];
    const float* be1 = (const float*)d_in[12];
    const float* g2  = (const float*)d_in[13];
    const float* be2 = (const float*)d_in[14];
    float* out = (float*)d_out;

    encoder_fused<<<dim3(NDIM / 2), dim3(256), 0, stream>>>(
        x, inw, inb, ow, ob, w1, b1, w2, b2, w3, b3, g1, be1, g2, be2, out);
}